// Round 16
// baseline (880.328 us; speedup 1.0000x reference)
//
#include <hip/hip_runtime.h>
#include <math.h>

#define DD 48
#define HH 64
#define WW 128
#define VOL (DD*HH*WW)     // 393216 real voxels
#define PW 130             // padded W
#define PROWS (DD*HH)      // 3072 rows
#define PVOL (PROWS*PW)    // 399360 padded voxels
#define PVBYTES ((long)PVOL*64*2) // 51,118,080 bytes per padded bf16 volume
#define GUARD 16640L       // one padded row guard each side
#define NC 64

typedef __attribute__((ext_vector_type(8))) short bf16x8;
typedef __attribute__((ext_vector_type(4))) float f32x4;
typedef __attribute__((ext_vector_type(4))) unsigned int u32x4v;
typedef __attribute__((ext_vector_type(2))) unsigned int u32x2v;

__device__ __forceinline__ float bflo(unsigned int u){
    union { unsigned int i; float f; } x; x.i = u<<16; return x.f; }
__device__ __forceinline__ float bfhi(unsigned int u){
    union { unsigned int i; float f; } x; x.i = u & 0xffff0000u; return x.f; }
__device__ __forceinline__ float bf2f(unsigned short u){
    union { unsigned int i; float f; } x; x.i = ((unsigned int)u)<<16; return x.f; }
__device__ __forceinline__ unsigned short f2bf(float f){
    union { float f; unsigned int i; } x; x.f = f;
    unsigned int i = x.i;
    return (unsigned short)((i + 0x7fffu + ((i>>16)&1u)) >> 16);  // RNE
}

__device__ __forceinline__ void gload16(const void* g, void* l){
    __builtin_amdgcn_global_load_lds(
        (const __attribute__((address_space(1))) void*)g,
        (__attribute__((address_space(3))) void*)l, 16, 0, 0);
}

// ================= merged weight prep (one launch) =================
__global__ void k_prep_all(
    const float* __restrict__ w_a1, const float* __restrict__ w_a2,
    const float* __restrict__ wc1,  const float* __restrict__ wnin,
    const float* __restrict__ wc2,  const float* __restrict__ w1s,
    const float* __restrict__ w2s,  const float* __restrict__ wp1,
    const float* __restrict__ wp2,  const float* __restrict__ wp3,
    unsigned short* __restrict__ wa1t, unsigned short* __restrict__ wa2t,
    unsigned short* __restrict__ wc1t, unsigned short* __restrict__ nint,
    unsigned short* __restrict__ wt2,  unsigned short* __restrict__ Mt,
    float* __restrict__ wpt)
{
    int b = blockIdx.x, tid = threadIdx.x;
    if (b < 1296){                      // [k=27][co][ci] bf16 repack x3 (432 blocks each)
        int which = b/432, bb = b - which*432;
        int idx = bb*256 + tid;
        if (idx < 27*64*64){
            const float* src = which==0 ? w_a1 : (which==1 ? w_a2 : wc1);
            unsigned short* dst = which==0 ? wa1t : (which==1 ? wa2t : wc1t);
            int ci = idx & 63; int t = idx >> 6; int co = t & 63; int k = t >> 6;
            dst[idx] = f2bf(src[(co*64+ci)*27 + k]);
        }
    } else if (b < 1376){               // M_i = W1 + W2@W1 -> bf16 (80 blocks)
        int idx = (b-1296)*256 + tid;
        int i = idx >> 12; int r = idx & 4095;
        int co = r >> 6; int ci = r & 63;
        const float* W1 = w1s + i*4096;
        const float* W2 = w2s + i*4096;
        float m = W1[co*64+ci];
        for (int k=0;k<64;++k) m += W2[co*64+k]*W1[k*64+ci];
        Mt[idx] = f2bf(m);
    } else if (b < 1392){               // nin bf16 (16 blocks)
        int idx = (b-1376)*256 + tid;
        nint[idx] = f2bf(wnin[idx]);
    } else if (b < 1400){               // head taps [32][64] bf16 (8 blocks)
        int idx = (b-1392)*256 + tid;
        int co = idx & 63; int row = idx >> 6;
        float v = (row < 27) ? wc2[co*27 + row] : 0.f;
        wt2[row*64 + co] = f2bf(v);
    } else {                            // pool-conv weight transpose x3 (48 blocks)
        int bb = b - 1400;
        int which = bb/16;
        int idx = (bb - which*16)*256 + tid;
        const float* src = which==0 ? wp1 : (which==1 ? wp2 : wp3);
        int ci = idx >> 6; int co = idx & 63;
        wpt[which*4096 + idx] = src[co*64+ci];
    }
}

// ============ zero the pad columns (w=-1, w=128) of both padded volumes ============
__global__ __launch_bounds__(256) void k_zeropad(unsigned short* __restrict__ pv0,
                                                 unsigned short* __restrict__ pv1){
    int idx = blockIdx.x*256 + threadIdx.x;      // 98,304 = 12,288 seg x 8 parts
    int seg = idx >> 3, part = idx & 7;
    int vol = seg / 6144; int r2 = seg - vol*6144;
    int row = r2 >> 1; int col = (r2 & 1) ? 129 : 0;
    long boff = ((long)row*130 + col)*128 + part*16;
    u32x4v z = {0,0,0,0};
    char* base = (char*)(vol ? pv1 : pv0);
    *(u32x4v*)(base + boff) = z;
}

// ============ fvl [64][VOL] fp32 -> padded [PVOL][64] bf16 (LDS transpose) ============
__global__ __launch_bounds__(256) void k_tobf16v(const float* __restrict__ src,
                                                 unsigned short* __restrict__ dst){
    __shared__ unsigned short lds[64*66];
    int tid = threadIdx.x;
    long vbase = (long)blockIdx.x*64;
    int d = (int)(vbase >> 13);
    int h = (int)((vbase >> 7) & 63);
    int w0 = (int)(vbase & 127);
    long pbase = ((long)(d*64+h)*PW + w0 + 1);
    int v = tid & 63;
    int cg = tid >> 6;
#pragma unroll
    for (int k=0;k<16;++k){
        int ci = cg*16 + k;
        lds[v*66 + ci] = f2bf(src[(long)ci*VOL + vbase + v]);
    }
    __syncthreads();
#pragma unroll
    for (int it=0; it<2; ++it){
        int chunk = it*256 + tid;
        int vv = chunk >> 3, gp = chunk & 7;
        const unsigned short* s = lds + vv*66 + gp*8;
        unsigned int w0_ = (unsigned)s[0] | ((unsigned)s[1]<<16);
        unsigned int w1_ = (unsigned)s[2] | ((unsigned)s[3]<<16);
        unsigned int w2_ = (unsigned)s[4] | ((unsigned)s[5]<<16);
        unsigned int w3_ = (unsigned)s[6] | ((unsigned)s[7]<<16);
        u32x4v q = {w0_,w1_,w2_,w3_};
        *(u32x4v*)(dst + (pbase+vv)*64 + gp*8) = q;
    }
}

// ============ MFMA conv3x3x3: LDS-staged via global_load_lds (R7, unchanged) ============
template<bool AUX, bool RELU>
__global__ __launch_bounds__(256,2) void k_conv3m(
    const unsigned short* __restrict__ in, const unsigned short* __restrict__ wt,
    const unsigned short* __restrict__ aux, const unsigned short* __restrict__ auxw,
    unsigned short* __restrict__ out)
{
    __shared__ __align__(16) char sA[36864];
    __shared__ __align__(16) char sB[33280];

    const int tid  = threadIdx.x;
    const int lane = tid & 63;
    const int wave = tid >> 6;
    const int ll = lane & 15;
    const int kg = lane >> 4;
    const int bid = blockIdx.x;
    const int wid = ((bid & 7) * 192) + (bid >> 3);
    const int vbr = wid*256;
    const int d  = vbr >> 13;
    const int h0 = (vbr >> 7) & 63;
    const int my_h  = h0 + (wave >> 1);
    const int my_w0 = (wave & 1) * 64;
    const long pvb = (long)(d*64 + my_h)*PW + my_w0 + 1;

    const char* inb = (const char*)in;
    const char* wtb = (const char*)wt;

    f32x4 acc[4][4];
#pragma unroll
    for (int a=0;a<4;++a)
#pragma unroll
        for (int b=0;b<4;++b) acc[a][b] = (f32x4){0.f,0.f,0.f,0.f};

#pragma unroll
    for (int kd=0; kd<3; ++kd){
        const int dd = d + kd - 1;
        if ((unsigned)dd >= 48u) continue;
        const long rowstart = ((long)(dd*64 + h0 - 1)) * 130;
#pragma unroll
        for (int khalf=0; khalf<2; ++khalf){
            __syncthreads();
#pragma unroll
            for (int rnd=0; rnd<9; ++rnd){
                int j = rnd*4096 + tid*16;
                int q = j ^ (((j>>7)&3)<<4);
                const char* src = wtb + (long)(kd*9 + (q>>12))*8192
                                      + (long)((q>>6)&63)*128 + khalf*64 + (q&63);
                gload16(src, sA + j);
            }
#pragma unroll
            for (int rnd=0; rnd<8; ++rnd){
                int j = rnd*4096 + tid*16;
                int q = j ^ (((j>>7)&3)<<4);
                const char* src = inb + (rowstart + (q>>6))*128 + khalf*64 + (q&63);
                gload16(src, sB + j);
            }
            if (tid < 32){
                int j = 32768 + tid*16;
                int q = j ^ (((j>>7)&3)<<4);
                const char* src = inb + (rowstart + (q>>6))*128 + khalf*64 + (q&63);
                gload16(src, sB + j);
            }
            __syncthreads();
#pragma unroll
            for (int kh=0; kh<3; ++kh){
                const int hh = my_h + kh - 1;
                if ((unsigned)hh >= 64u) continue;
                const int rr = (wave>>1) + kh;
#pragma unroll
                for (int kw=0; kw<3; ++kw){
                    const int tap_rel = kh*3 + kw;
                    bf16x8 Af[4], Bf[4];
#pragma unroll
                    for (int t=0;t<4;++t){
                        int qa = tap_rel*4096 + (t*16+ll)*64 + kg*16;
                        Af[t] = *(const bf16x8*)(sA + (qa ^ (((qa>>7)&3)<<4)));
                    }
#pragma unroll
                    for (int vt=0; vt<4; ++vt){
                        int vrel = rr*130 + my_w0 + vt*16 + ll + kw;
                        int qb = vrel*64 + kg*16;
                        Bf[vt] = *(const bf16x8*)(sB + (qb ^ (((qb>>7)&3)<<4)));
                    }
#pragma unroll
                    for (int vt=0; vt<4; ++vt)
#pragma unroll
                        for (int t=0; t<4; ++t)
                            acc[t][vt] = __builtin_amdgcn_mfma_f32_16x16x32_bf16(Af[t], Bf[vt], acc[t][vt], 0,0,0);
                }
            }
        }
    }

    if (AUX){
        bf16x8 Aa[2][4], Ba[2][4];
#pragma unroll
        for (int half=0; half<2; ++half){
            const int ko = half*32 + kg*8;
#pragma unroll
            for (int t=0;t<4;++t)
                Aa[half][t] = *(const bf16x8*)(auxw + (t*16+ll)*64 + ko);
#pragma unroll
            for (int vt=0; vt<4; ++vt)
                Ba[half][vt] = *(const bf16x8*)(aux + (pvb + vt*16 + ll)*64 + ko);
        }
#pragma unroll
        for (int half=0; half<2; ++half)
#pragma unroll
            for (int vt=0; vt<4; ++vt)
#pragma unroll
                for (int t=0;t<4;++t)
                    acc[t][vt] = __builtin_amdgcn_mfma_f32_16x16x32_bf16(Aa[half][t], Ba[half][vt], acc[t][vt], 0,0,0);
    }

#pragma unroll
    for (int vt=0; vt<4; ++vt){
        unsigned short* op = out + (pvb + vt*16 + ll)*64 + kg*4;
#pragma unroll
        for (int t=0;t<4;++t){
            float r0 = acc[t][vt][0], r1 = acc[t][vt][1], r2 = acc[t][vt][2], r3 = acc[t][vt][3];
            if (RELU){ r0=fmaxf(r0,0.f); r1=fmaxf(r1,0.f); r2=fmaxf(r2,0.f); r3=fmaxf(r3,0.f); }
            unsigned int lo = (unsigned)f2bf(r0) | ((unsigned)f2bf(r1)<<16);
            unsigned int hi = (unsigned)f2bf(r2) | ((unsigned)f2bf(r3)<<16);
            u32x2v q = {lo, hi};
            *(u32x2v*)(op + t*16) = q;
        }
    }
}

// ============ HEAD: conv3(x,wc1)+relu FUSED with tap-GEMM (R13, unchanged) ============
__global__ __launch_bounds__(256,2) void k_conv3h(
    const unsigned short* __restrict__ in, const unsigned short* __restrict__ wt,
    const unsigned short* __restrict__ wt2, unsigned short* __restrict__ t)
{
    __shared__ __align__(16) char sA[36864];
    __shared__ __align__(16) char sB[33280];

    const int tid  = threadIdx.x;
    const int lane = tid & 63;
    const int wave = tid >> 6;
    const int ll = lane & 15;
    const int kg = lane >> 4;
    const int bid = blockIdx.x;
    const int wid = ((bid & 7) * 192) + (bid >> 3);
    const int vbr = wid*256;
    const int d  = vbr >> 13;
    const int h0 = (vbr >> 7) & 63;
    const int my_h  = h0 + (wave >> 1);
    const int my_w0 = (wave & 1) * 64;
    const long pvb = (long)(d*64 + my_h)*PW + my_w0 + 1;

    const char* inb = (const char*)in;
    const char* wtb = (const char*)wt;

    f32x4 acc[4][4];
#pragma unroll
    for (int a=0;a<4;++a)
#pragma unroll
        for (int b=0;b<4;++b) acc[a][b] = (f32x4){0.f,0.f,0.f,0.f};

#pragma unroll
    for (int kd=0; kd<3; ++kd){
        const int dd = d + kd - 1;
        if ((unsigned)dd >= 48u) continue;
        const long rowstart = ((long)(dd*64 + h0 - 1)) * 130;
#pragma unroll
        for (int khalf=0; khalf<2; ++khalf){
            __syncthreads();
#pragma unroll
            for (int rnd=0; rnd<9; ++rnd){
                int j = rnd*4096 + tid*16;
                int q = j ^ (((j>>7)&3)<<4);
                const char* src = wtb + (long)(kd*9 + (q>>12))*8192
                                      + (long)((q>>6)&63)*128 + khalf*64 + (q&63);
                gload16(src, sA + j);
            }
#pragma unroll
            for (int rnd=0; rnd<8; ++rnd){
                int j = rnd*4096 + tid*16;
                int q = j ^ (((j>>7)&3)<<4);
                const char* src = inb + (rowstart + (q>>6))*128 + khalf*64 + (q&63);
                gload16(src, sB + j);
            }
            if (tid < 32){
                int j = 32768 + tid*16;
                int q = j ^ (((j>>7)&3)<<4);
                const char* src = inb + (rowstart + (q>>6))*128 + khalf*64 + (q&63);
                gload16(src, sB + j);
            }
            __syncthreads();
#pragma unroll
            for (int kh=0; kh<3; ++kh){
                const int hh = my_h + kh - 1;
                if ((unsigned)hh >= 64u) continue;
                const int rr = (wave>>1) + kh;
#pragma unroll
                for (int kw=0; kw<3; ++kw){
                    const int tap_rel = kh*3 + kw;
                    bf16x8 Af[4], Bf[4];
#pragma unroll
                    for (int tt=0;tt<4;++tt){
                        int qa = tap_rel*4096 + (tt*16+ll)*64 + kg*16;
                        Af[tt] = *(const bf16x8*)(sA + (qa ^ (((qa>>7)&3)<<4)));
                    }
#pragma unroll
                    for (int vt=0; vt<4; ++vt){
                        int vrel = rr*130 + my_w0 + vt*16 + ll + kw;
                        int qb = vrel*64 + kg*16;
                        Bf[vt] = *(const bf16x8*)(sB + (qb ^ (((qb>>7)&3)<<4)));
                    }
#pragma unroll
                    for (int vt=0; vt<4; ++vt)
#pragma unroll
                        for (int tt=0; tt<4; ++tt)
                            acc[tt][vt] = __builtin_amdgcn_mfma_f32_16x16x32_bf16(Af[tt], Bf[vt], acc[tt][vt], 0,0,0);
                }
            }
        }
    }

    // --- fused tap-GEMM epilogue ---
    __syncthreads();
    char* myL = sA + wave*8192;
#pragma unroll
    for (int vt=0; vt<4; ++vt){
        const int row = vt*16 + ll;
        const int sw = (row & 7) << 4;
#pragma unroll
        for (int tt=0;tt<4;++tt){
            float r0 = fmaxf(acc[tt][vt][0],0.f), r1 = fmaxf(acc[tt][vt][1],0.f);
            float r2 = fmaxf(acc[tt][vt][2],0.f), r3 = fmaxf(acc[tt][vt][3],0.f);
            unsigned int lo = (unsigned)f2bf(r0) | ((unsigned)f2bf(r1)<<16);
            unsigned int hi = (unsigned)f2bf(r2) | ((unsigned)f2bf(r3)<<16);
            u32x2v q = {lo, hi};
            int colb = kg*8 + tt*32;
            *(u32x2v*)(myL + row*128 + (colb ^ sw)) = q;
        }
    }
    f32x4 acc2[2][4];
#pragma unroll
    for (int a=0;a<2;++a)
#pragma unroll
        for (int b=0;b<4;++b) acc2[a][b] = (f32x4){0.f,0.f,0.f,0.f};
#pragma unroll
    for (int half=0; half<2; ++half){
        const int ko = half*32 + kg*8;
        bf16x8 afr[2];
#pragma unroll
        for (int tl=0;tl<2;++tl)
            afr[tl] = *(const bf16x8*)(wt2 + (tl*16+ll)*64 + ko);
#pragma unroll
        for (int vt=0; vt<4; ++vt){
            const int row = vt*16 + ll;
            const int sw = (row & 7) << 4;
            int colb = half*64 + kg*16;
            bf16x8 bfr = *(const bf16x8*)(myL + row*128 + (colb ^ sw));
#pragma unroll
            for (int tl=0;tl<2;++tl)
                acc2[tl][vt] = __builtin_amdgcn_mfma_f32_16x16x32_bf16(afr[tl], bfr, acc2[tl][vt], 0,0,0);
        }
    }
#pragma unroll
    for (int vt=0; vt<4; ++vt){
        long vx = pvb + vt*16 + ll;
#pragma unroll
        for (int tl=0;tl<2;++tl){
#pragma unroll
            for (int r=0;r<4;++r){
                int tap = tl*16 + kg*4 + r;
                if (tap < 27) t[(long)tap*PVOL + vx] = f2bf(acc2[tl][vt][r]);
            }
        }
    }
}

// ============ FUSED residual chain (R9, unchanged) ============
__global__ __launch_bounds__(256,3) void k_chain(const unsigned short* __restrict__ in,
        const unsigned short* __restrict__ Mt, unsigned short* __restrict__ out){
    __shared__ __align__(16) char sX[4][8192];
    const int lane = threadIdx.x & 63;
    const int wave = threadIdx.x >> 6;
    const int ll = lane & 15;
    const int kg = lane >> 4;
    const long vb = (long)blockIdx.x*256 + wave*64;
    char* myL = sX[wave];

    bf16x8 B[2][4];
#pragma unroll
    for (int half=0; half<2; ++half){
        const int ko = half*32 + kg*8;
#pragma unroll
        for (int vt=0; vt<4; ++vt)
            B[half][vt] = *(const bf16x8*)(in + (vb+vt*16+ll)*64 + ko);
    }

#pragma unroll
    for (int s=0; s<5; ++s){
        const unsigned short* wt = Mt + s*4096;
        bf16x8 A[2][4];
#pragma unroll
        for (int half=0; half<2; ++half){
            const int ko = half*32 + kg*8;
#pragma unroll
            for (int t=0;t<4;++t)
                A[half][t] = *(const bf16x8*)(wt + (t*16+ll)*64 + ko);
        }
        f32x4 acc[4][4];
#pragma unroll
        for (int a=0;a<4;++a)
#pragma unroll
            for (int b=0;b<4;++b) acc[a][b] = (f32x4){0.f,0.f,0.f,0.f};
#pragma unroll
        for (int half=0; half<2; ++half)
#pragma unroll
            for (int vt=0; vt<4; ++vt)
#pragma unroll
                for (int t=0;t<4;++t)
                    acc[t][vt] = __builtin_amdgcn_mfma_f32_16x16x32_bf16(A[half][t], B[half][vt], acc[t][vt], 0,0,0);

        if (s < 4){
#pragma unroll
            for (int vt=0; vt<4; ++vt){
                const int row = vt*16 + ll;
                const int sw = (row & 7) << 4;
#pragma unroll
                for (int t=0;t<4;++t){
                    float r0 = fmaxf(acc[t][vt][0],0.f), r1 = fmaxf(acc[t][vt][1],0.f);
                    float r2 = fmaxf(acc[t][vt][2],0.f), r3 = fmaxf(acc[t][vt][3],0.f);
                    unsigned int lo = (unsigned)f2bf(r0) | ((unsigned)f2bf(r1)<<16);
                    unsigned int hi = (unsigned)f2bf(r2) | ((unsigned)f2bf(r3)<<16);
                    u32x2v q = {lo, hi};
                    int colb = kg*8 + t*32;
                    *(u32x2v*)(myL + row*128 + (colb ^ sw)) = q;
                }
            }
#pragma unroll
            for (int half=0; half<2; ++half){
#pragma unroll
                for (int vt=0; vt<4; ++vt){
                    const int row = vt*16 + ll;
                    const int sw = (row & 7) << 4;
                    int colb = half*64 + kg*16;
                    B[half][vt] = *(const bf16x8*)(myL + row*128 + (colb ^ sw));
                }
            }
        } else {
#pragma unroll
            for (int vt=0; vt<4; ++vt){
                unsigned short* op = out + (vb+vt*16+ll)*64 + kg*4;
#pragma unroll
                for (int t=0;t<4;++t){
                    float r0 = fmaxf(acc[t][vt][0],0.f), r1 = fmaxf(acc[t][vt][1],0.f);
                    float r2 = fmaxf(acc[t][vt][2],0.f), r3 = fmaxf(acc[t][vt][3],0.f);
                    unsigned int lo = (unsigned)f2bf(r0) | ((unsigned)f2bf(r1)<<16);
                    unsigned int hi = (unsigned)f2bf(r2) | ((unsigned)f2bf(r3)<<16);
                    u32x2v q = {lo, hi};
                    *(u32x2v*)(op + t*16) = q;
                }
            }
        }
    }
}

// ============ head stage 2: 4 voxels/thread (R14, unchanged) ============
__global__ __launch_bounds__(256) void k_heads(const unsigned short* __restrict__ t,
        const float* __restrict__ bias, float* __restrict__ out){
    int g = blockIdx.x*256 + threadIdx.x;
    int v0 = g*4;
    int w0 = v0 & 127; int h = (v0>>7)&63; int d = v0>>13;
    long p0 = (long)(d*64+h)*PW + w0 + 1;
    float b0 = bias[0];
    float s0=b0, s1=b0, s2=b0, s3=b0;
#pragma unroll
    for (int kd=0;kd<3;++kd){
#pragma unroll
      for (int kh=0;kh<3;++kh){
#pragma unroll
        for (int kw=0;kw<3;++kw){
            const int tap = (kd*3+kh)*3+kw;
            const long dvp = (long)((kd-1)*64 + (kh-1))*PW + (kw-1);
            bool okdh = ((unsigned)(d+kd-1)<48u) && ((unsigned)(h+kh-1)<64u);
            const unsigned short* tp = t + (long)tap*PVOL;
            bool ok0 = okdh && ((unsigned)(w0+0+kw-1)<128u);
            bool ok1 = okdh && ((unsigned)(w0+1+kw-1)<128u);
            bool ok2 = okdh && ((unsigned)(w0+2+kw-1)<128u);
            bool ok3 = okdh && ((unsigned)(w0+3+kw-1)<128u);
            long a0 = ok0 ? (p0+0+dvp) : p0;
            long a1 = ok1 ? (p0+1+dvp) : p0;
            long a2 = ok2 ? (p0+2+dvp) : p0;
            long a3 = ok3 ? (p0+3+dvp) : p0;
            float x0 = bf2f(tp[a0]);
            float x1 = bf2f(tp[a1]);
            float x2 = bf2f(tp[a2]);
            float x3 = bf2f(tp[a3]);
            s0 += ok0 ? x0 : 0.f;
            s1 += ok1 ? x1 : 0.f;
            s2 += ok2 ? x2 : 0.f;
            s3 += ok3 ? x3 : 0.f;
        }
      }
    }
    f32x4 r = {s0,s1,s2,s3};
    *(f32x4*)(out + v0) = r;
}

// ============ pool stage 1: S3 cell sums (unchanged) ============
__global__ __launch_bounds__(256) void k_pool3(const unsigned short* __restrict__ in,
                                               float* __restrict__ S3){
    __shared__ float sm[32*68];
    int tid = threadIdx.x;
    int cg = tid & 7, part = tid >> 3;
    int cell = blockIdx.x;
    int Z = cell >> 8, Y = (cell >> 4) & 15, X = cell & 15;
    float a[8];
#pragma unroll
    for (int j=0;j<8;++j) a[j]=0.f;
#pragma unroll
    for (int j=0;j<3;++j){
        int i = part*3 + j;
        int di = i >> 5, rem = i & 31, hi = rem >> 3, wi = rem & 7;
        long p = ((long)((3*Z+di)*64 + 4*Y+hi))*PW + 8*X+wi + 1;
        u32x4v q = *(const u32x4v*)(in + p*64 + cg*8);
#pragma unroll
        for (int e=0;e<4;++e){ a[e*2] += bflo(q[e]); a[e*2+1] += bfhi(q[e]); }
    }
#pragma unroll
    for (int j=0;j<8;++j) sm[part*68 + cg*8 + j] = a[j];
    __syncthreads();
    if (tid < 64){
        float s=0.f;
        for (int r=0;r<32;++r) s += sm[r*68 + tid];
        S3[tid*4096 + cell] = s;
    }
}

// ============ p2 sums from S3 (unchanged) ============
__global__ __launch_bounds__(256) void k_pool2(const float* __restrict__ S3,
                                               float* __restrict__ P2){
    int idx = blockIdx.x*256 + threadIdx.x;
    int cell = idx & 511; int c = idx >> 9;
    int z = cell >> 6, y = (cell >> 3) & 7, x = cell & 7;
    const float* b = S3 + c*4096;
    float s = 0.f;
#pragma unroll
    for (int a2=0;a2<2;++a2)
#pragma unroll
        for (int b2=0;b2<2;++b2)
#pragma unroll
            for (int e=0;e<2;++e)
                s += b[((2*z+a2)<<8) + ((2*y+b2)<<4) + (2*x+e)];
    P2[c*512 + cell] = s;
}

// ============ g + gc from S3 (unchanged) ============
__global__ void k_gcm(const float* __restrict__ S3, const float* __restrict__ wp0,
                      float* __restrict__ gc){
    __shared__ float sm[4][64];
    __shared__ float sg[64];
    int tid = threadIdx.x;
    int c = tid & 63, part = tid >> 6;
    float s = 0.f;
    const float* row = S3 + c*4096 + part*1024;
    for (int i=0;i<1024;i+=4){
        f32x4 q = *(const f32x4*)(row + i);
        s += q[0]+q[1]+q[2]+q[3];
    }
    sm[part][c] = s;
    __syncthreads();
    if (tid < 64){
        sg[tid] = (sm[0][tid]+sm[1][tid]+sm[2][tid]+sm[3][tid]) * (1.0f/(float)VOL);
    }
    __syncthreads();
    if (tid < 64){
        float g=0.f;
        for (int ci=0;ci<64;++ci) g += wp0[tid*64+ci]*sg[ci];
        gc[tid] = g;
    }
}

// ============ p4 sums (unchanged) ============
__global__ __launch_bounds__(256) void k_pool4(const unsigned short* __restrict__ in,
                                               float* __restrict__ P4){
    __shared__ float sm[32*68];
    int tid = threadIdx.x;
    int cg = tid & 7, part = (tid >> 3) & 3, slot = tid >> 5;
    int cell = blockIdx.x*8 + slot;
    int z = cell / 800; int rem = cell - z*800; int y = rem / 25; int x = rem - y*25;
    int a2 = part >> 1, b2 = part & 1;
    float a[8];
#pragma unroll
    for (int j=0;j<8;++j) a[j]=0.f;
#pragma unroll
    for (int e=0;e<5;++e){
        long p = ((long)((2*z+a2)*64 + 2*y+b2))*PW + 5*x+e + 1;
        u32x4v q = *(const u32x4v*)(in + p*64 + cg*8);
#pragma unroll
        for (int k=0;k<4;++k){ a[k*2] += bflo(q[k]); a[k*2+1] += bfhi(q[k]); }
    }
#pragma unroll
    for (int j=0;j<8;++j) sm[(slot*4+part)*68 + cg*8 + j] = a[j];
    __syncthreads();
#pragma unroll
    for (int r=0;r<2;++r){
        int o = r*256 + tid;
        int c = o >> 3, s = o & 7;
        float v = sm[(s*4+0)*68 + c] + sm[(s*4+1)*68 + c]
                + sm[(s*4+2)*68 + c] + sm[(s*4+3)*68 + c];
        P4[(long)c*19200 + blockIdx.x*8 + s] = v;
    }
}

// ============ 1x1 conv fp32 on pooled SUMS (unchanged) ============
__global__ void k_conv1(const float* __restrict__ in, const float* __restrict__ wt,
                        float* __restrict__ out, int vol, float scale){
    int v = blockIdx.x*256 + threadIdx.x;
    if (v >= vol) return;
    float acc[64];
#pragma unroll
    for (int i=0;i<64;++i) acc[i]=0.f;
    for (int ci=0; ci<64; ++ci){
        float xv = in[ci*vol + v];
        const float* wr = wt + ci*64;
#pragma unroll
        for (int co=0; co<64; ++co) acc[co] = fmaf(wr[co], xv, acc[co]);
    }
    float* op = out + (long)v*64;
#pragma unroll
    for (int q=0;q<16;++q){
        f32x4 t = {acc[q*4]*scale, acc[q*4+1]*scale, acc[q*4+2]*scale, acc[q*4+3]*scale};
        *(f32x4*)(op + q*4) = t;
    }
}

// ============ trilinear gather ============
__device__ __forceinline__ void tri_setup(int d,int h,int w,int gd,int gh,int gw,
                                          int* o, float* wt){
    float fz = (d+0.5f)*((float)gd/(float)DD) - 0.5f;
    float fy = (h+0.5f)*((float)gh/(float)HH) - 0.5f;
    float fx = (w+0.5f)*((float)gw/(float)WW) - 0.5f;
    float z0f = floorf(fz), y0f = floorf(fy), x0f = floorf(fx);
    float tz = fz - z0f, ty = fy - y0f, tx = fx - x0f;
    int z0 = (int)z0f, y0 = (int)y0f, x0 = (int)x0f;
    int z1 = z0+1, y1 = y0+1, x1 = x0+1;
    z0 = min(max(z0,0),gd-1); z1 = min(max(z1,0),gd-1);
    y0 = min(max(y0,0),gh-1); y1 = min(max(y1,0),gh-1);
    x0 = min(max(x0,0),gw-1); x1 = min(max(x1,0),gw-1);
    o[0] = (z0*gh+y0)*gw+x0; wt[0] = (1-tz)*(1-ty)*(1-tx);
    o[1] = (z0*gh+y0)*gw+x1; wt[1] = (1-tz)*(1-ty)*tx;
    o[2] = (z0*gh+y1)*gw+x0; wt[2] = (1-tz)*ty*(1-tx);
    o[3] = (z0*gh+y1)*gw+x1; wt[3] = (1-tz)*ty*tx;
    o[4] = (z1*gh+y0)*gw+x0; wt[4] = tz*(1-ty)*(1-tx);
    o[5] = (z1*gh+y0)*gw+x1; wt[5] = tz*(1-ty)*tx;
    o[6] = (z1*gh+y1)*gw+x0; wt[6] = tz*ty*(1-tx);
    o[7] = (z1*gh+y1)*gw+x1; wt[7] = tz*ty*tx;
}

// combine-LIGHT: out = relu((xc + 0.25*(gc+up2+up3+up4))/2) -> xv bf16 ONLY
// (fp32 channel-major output moved to dedicated k_xpose)
__global__ __launch_bounds__(256) void k_combine(
        const unsigned short* __restrict__ xc, const float* __restrict__ gc,
        const float* __restrict__ p2, const float* __restrict__ p3,
        const float* __restrict__ p4, unsigned short* __restrict__ xv){
    int tid = threadIdx.x;
    const int bid = blockIdx.x;
    const int wid = ((bid & 7) * 192) + (bid >> 3);   // 1536 blocks, bijective
    long v = (long)wid*256 + tid;
    int w = v & 127; int h = (v>>7)&63; int d = v>>13;
    long p = (long)(d*64+h)*PW + w + 1;
    int o2[8], o3[8], o4[8];
    float w2_[8], w3_[8], w4_[8];
    tri_setup(d,h,w, 8,8,8,    o2, w2_);
    tri_setup(d,h,w, 16,16,16, o3, w3_);
    tri_setup(d,h,w, 24,32,25, o4, w4_);
#pragma unroll
    for (int half=0; half<2; ++half){
        float res[32];
#pragma unroll
        for (int j=0;j<32;++j) res[j] = gc[half*32+j];
#pragma unroll
        for (int t=0;t<8;++t){
            const float* b2 = p2 + (long)o2[t]*64 + half*32;
#pragma unroll
            for (int q=0;q<8;++q){
                f32x4 x4 = *(const f32x4*)(b2 + q*4);
                res[q*4+0] = fmaf(w2_[t], x4[0], res[q*4+0]);
                res[q*4+1] = fmaf(w2_[t], x4[1], res[q*4+1]);
                res[q*4+2] = fmaf(w2_[t], x4[2], res[q*4+2]);
                res[q*4+3] = fmaf(w2_[t], x4[3], res[q*4+3]);
            }
        }
#pragma unroll
        for (int t=0;t<8;++t){
            const float* b3 = p3 + (long)o3[t]*64 + half*32;
#pragma unroll
            for (int q=0;q<8;++q){
                f32x4 x4 = *(const f32x4*)(b3 + q*4);
                res[q*4+0] = fmaf(w3_[t], x4[0], res[q*4+0]);
                res[q*4+1] = fmaf(w3_[t], x4[1], res[q*4+1]);
                res[q*4+2] = fmaf(w3_[t], x4[2], res[q*4+2]);
                res[q*4+3] = fmaf(w3_[t], x4[3], res[q*4+3]);
            }
        }
#pragma unroll
        for (int t=0;t<8;++t){
            const float* b4 = p4 + (long)o4[t]*64 + half*32;
#pragma unroll
            for (int q=0;q<8;++q){
                f32x4 x4 = *(const f32x4*)(b4 + q*4);
                res[q*4+0] = fmaf(w4_[t], x4[0], res[q*4+0]);
                res[q*4+1] = fmaf(w4_[t], x4[1], res[q*4+1]);
                res[q*4+2] = fmaf(w4_[t], x4[2], res[q*4+2]);
                res[q*4+3] = fmaf(w4_[t], x4[3], res[q*4+3]);
            }
        }
        const u32x4v* xq = (const u32x4v*)(xc + p*64 + half*32);
#pragma unroll
        for (int q=0;q<4;++q){
            u32x4v qv = xq[q];
            unsigned int pk[4];
#pragma unroll
            for (int e=0;e<4;++e){
                int j = q*8 + e*2;
                float r0 = fmaxf((bflo(qv[e]) + 0.25f*res[j])*0.5f, 0.f);
                float r1 = fmaxf((bfhi(qv[e]) + 0.25f*res[j+1])*0.5f, 0.f);
                pk[e] = (unsigned)f2bf(r0) | ((unsigned)f2bf(r1)<<16);
            }
            u32x4v pq = {pk[0],pk[1],pk[2],pk[3]};
            *(u32x4v*)(xv + p*64 + half*32 + q*8) = pq;
        }
    }
}

// ============ dedicated transpose: xv bf16 [PVOL][64] -> xout fp32 [64][VOL] ============
// 256-voxel tiles; LDS uint[32][261] (261%32==5 -> conflict-free both phases);
// coalesced 128B/thread reads, nt fp32 vector stores, XCD swizzle.
__global__ __launch_bounds__(256) void k_xpose(const unsigned short* __restrict__ xv,
                                               float* __restrict__ xout){
    __shared__ unsigned int lds32[32][261];
    int tid = threadIdx.x;
    const int bid = blockIdx.x;
    const int wid = ((bid & 7) * 192) + (bid >> 3);   // 1536 blocks, bijective
    long vb = (long)wid*256;
    // phase 1: thread = one voxel, read its 64 ch (128B), scatter ch-pairs to LDS
    {
        long gv = vb + tid;
        int row = (int)(gv >> 7); int w = (int)(gv & 127);
        long p = (long)row*PW + w + 1;
        const u32x4v* src = (const u32x4v*)(xv + p*64);
#pragma unroll
        for (int g=0; g<8; ++g){
            u32x4v q = src[g];
#pragma unroll
            for (int e=0;e<4;++e)
                lds32[g*4+e][tid] = q[e];
        }
    }
    __syncthreads();
    // phase 2: thread = (channel c, 64-vox run part); write contiguous fp32
    int c = tid & 63, part = tid >> 6;
    int cp = c >> 1; bool hiw = (c & 1);
    int v0 = part*64;
    float* op = xout + (long)c*VOL + vb + v0;
#pragma unroll
    for (int k=0;k<16;++k){
        f32x4 o;
#pragma unroll
        for (int e=0;e<4;++e){
            unsigned int u = lds32[cp][v0 + k*4 + e];
            o[e] = hiw ? bfhi(u) : bflo(u);
        }
        __builtin_nontemporal_store(o, (f32x4*)(op + k*4));
    }
}

// ================= workspace layout (bytes) =================
constexpr long RPV = GUARD + PVBYTES + GUARD;
constexpr long OFF_PV0R = 0;
constexpr long OFF_PV1R = RPV;
constexpr long OFF_WA1 = 2*RPV;
constexpr long OFF_WA2 = OFF_WA1 + 221184;
constexpr long OFF_WC1 = OFF_WA2 + 221184;
constexpr long OFF_NIN = OFF_WC1 + 221184;
constexpr long OFF_MT  = OFF_NIN + 8192;
constexpr long OFF_WT2 = OFF_MT + 40960;
constexpr long OFF_WPT = OFF_WT2 + 4096;
constexpr long OFF_GC  = OFF_WPT + 49152;
constexpr long OFF_P2  = OFF_GC + 256;
constexpr long OFF_P2C = OFF_P2 + 131072;
constexpr long OFF_S3  = OFF_P2C + 131072;
constexpr long OFF_P3C = OFF_S3 + 1048576;
constexpr long OFF_P4  = OFF_P3C + 1048576;
constexpr long OFF_P4C = OFF_P4 + 4915200;
// end ~= 115.4 MB

extern "C" void kernel_launch(void* const* d_in, const int* in_sizes, int n_in,
                              void* d_out, int out_size, void* d_ws, size_t ws_size,
                              hipStream_t stream) {
    const float* fvl  = (const float*)d_in[0];
    const float* w_a1 = (const float*)d_in[1];
    const float* w_a2 = (const float*)d_in[2];
    const float* wnin = (const float*)d_in[3];
    const float* w1s  = (const float*)d_in[4];
    const float* w2s  = (const float*)d_in[5];
    const float* wp0  = (const float*)d_in[6];
    const float* wp1  = (const float*)d_in[7];
    const float* wp2  = (const float*)d_in[8];
    const float* wp3  = (const float*)d_in[9];
    const float* wc1  = (const float*)d_in[10];
    const float* wc2  = (const float*)d_in[11];
    const float* bc   = (const float*)d_in[12];

    char* ws = (char*)d_ws;
    unsigned short* PV0  = (unsigned short*)(ws + OFF_PV0R + GUARD);
    unsigned short* PV1  = (unsigned short*)(ws + OFF_PV1R + GUARD);
    unsigned short* wa1t = (unsigned short*)(ws + OFF_WA1);
    unsigned short* wa2t = (unsigned short*)(ws + OFF_WA2);
    unsigned short* wc1t = (unsigned short*)(ws + OFF_WC1);
    unsigned short* nint = (unsigned short*)(ws + OFF_NIN);
    unsigned short* Mt   = (unsigned short*)(ws + OFF_MT);
    unsigned short* wt2  = (unsigned short*)(ws + OFF_WT2);
    float* wpt  = (float*)(ws + OFF_WPT);
    float* gc   = (float*)(ws + OFF_GC);
    float* p2   = (float*)(ws + OFF_P2);
    float* p2c  = (float*)(ws + OFF_P2C);
    float* S3   = (float*)(ws + OFF_S3);
    float* p3c  = (float*)(ws + OFF_P3C);
    float* p4   = (float*)(ws + OFF_P4);
    float* p4c  = (float*)(ws + OFF_P4C);

    float* Xout = (float*)d_out;
    float* Cout = Xout + (long)NC*VOL;
    unsigned short* Tbuf = PV1;     // head t bf16 [27][PVOL], reuses PV1 (free after combine)

    const int GBR = VOL/256;     // 1536
    const int GBP = PVOL/256;    // 1560

    // zero only the pad columns (1.5MB instead of 102MB of memset)
    k_zeropad<<<384,256,0,stream>>>(PV0, PV1);

    // all weight prep in ONE launch
    k_prep_all<<<1448,256,0,stream>>>(w_a1, w_a2, wc1, wnin, wc2, w1s, w2s,
                                      wp1, wp2, wp3,
                                      wa1t, wa2t, wc1t, nint, wt2, Mt, wpt);
    k_tobf16v<<<VOL/64,256,0,stream>>>(fvl, PV0);

    // stage A/B: conv3 chain
    k_conv3m<false,false><<<GBR,256,0,stream>>>(PV0, wa1t, nullptr, nullptr, PV1);
    k_conv3m<true,false><<<GBR,256,0,stream>>>(PV1, wa2t, PV0, nint, PV0);

    // stage C: fused 5-stage residual chain PV0 -> PV1 (one kernel)
    k_chain<<<GBP,256,0,stream>>>(PV0, Mt, PV1);

    // stage D: pool pyramid
    k_pool3<<<4096,256,0,stream>>>(PV1, S3);
    k_gcm<<<1,256,0,stream>>>(S3, wp0, gc);
    k_pool2<<<128,256,0,stream>>>(S3, p2);
    k_pool4<<<2400,256,0,stream>>>(PV1, p4);
    k_conv1<<<2,256,0,stream>>>(p2, wpt + 0*4096, p2c, 512,   1.0f/768.0f);
    k_conv1<<<16,256,0,stream>>>(S3, wpt + 1*4096, p3c, 4096, 1.0f/96.0f);
    k_conv1<<<75,256,0,stream>>>(p4, wpt + 2*4096, p4c, 19200, 1.0f/20.0f);

    // combine-light: bf16 x into PV0 only
    k_combine<<<GBR,256,0,stream>>>(PV1, gc, p2c, p3c, p4c, PV0);
    // dedicated transpose: PV0 bf16 -> Xout fp32 channel-major
    k_xpose<<<GBR,256,0,stream>>>(PV0, Xout);

    // head: conv3(x,wc1)+relu fused with tap-GEMM -> Tbuf (PV1); then gather-sum
    k_conv3h<<<GBR,256,0,stream>>>(PV0, wc1t, wt2, Tbuf);
    k_heads<<<384,256,0,stream>>>(Tbuf, bc, Cout);
}

// Round 17
// 839.749 us; speedup vs baseline: 1.0483x; 1.0483x over previous
//
#include <hip/hip_runtime.h>
#include <math.h>

#define DD 48
#define HH 64
#define WW 128
#define VOL (DD*HH*WW)     // 393216 real voxels
#define PW 130             // padded W
#define PROWS (DD*HH)      // 3072 rows
#define PVOL (PROWS*PW)    // 399360 padded voxels
#define PVBYTES ((long)PVOL*64*2) // 51,118,080 bytes per padded bf16 volume
#define GUARD 16640L       // one padded row guard each side
#define NC 64

typedef __attribute__((ext_vector_type(8))) short bf16x8;
typedef __attribute__((ext_vector_type(4))) float f32x4;
typedef __attribute__((ext_vector_type(4))) unsigned int u32x4v;
typedef __attribute__((ext_vector_type(2))) unsigned int u32x2v;

__device__ __forceinline__ float bflo(unsigned int u){
    union { unsigned int i; float f; } x; x.i = u<<16; return x.f; }
__device__ __forceinline__ float bfhi(unsigned int u){
    union { unsigned int i; float f; } x; x.i = u & 0xffff0000u; return x.f; }
__device__ __forceinline__ float bf2f(unsigned short u){
    union { unsigned int i; float f; } x; x.i = ((unsigned int)u)<<16; return x.f; }
__device__ __forceinline__ unsigned short f2bf(float f){
    union { float f; unsigned int i; } x; x.f = f;
    unsigned int i = x.i;
    return (unsigned short)((i + 0x7fffu + ((i>>16)&1u)) >> 16);  // RNE
}

__device__ __forceinline__ void gload16(const void* g, void* l){
    __builtin_amdgcn_global_load_lds(
        (const __attribute__((address_space(1))) void*)g,
        (__attribute__((address_space(3))) void*)l, 16, 0, 0);
}

// ================= merged weight prep (one launch) =================
__global__ void k_prep_all(
    const float* __restrict__ w_a1, const float* __restrict__ w_a2,
    const float* __restrict__ wc1,  const float* __restrict__ wnin,
    const float* __restrict__ wc2,  const float* __restrict__ w1s,
    const float* __restrict__ w2s,  const float* __restrict__ wp1,
    const float* __restrict__ wp2,  const float* __restrict__ wp3,
    unsigned short* __restrict__ wa1t, unsigned short* __restrict__ wa2t,
    unsigned short* __restrict__ wc1t, unsigned short* __restrict__ nint,
    unsigned short* __restrict__ wt2,  unsigned short* __restrict__ Mt,
    float* __restrict__ wpt)
{
    int b = blockIdx.x, tid = threadIdx.x;
    if (b < 1296){                      // [k=27][co][ci] bf16 repack x3 (432 blocks each)
        int which = b/432, bb = b - which*432;
        int idx = bb*256 + tid;
        if (idx < 27*64*64){
            const float* src = which==0 ? w_a1 : (which==1 ? w_a2 : wc1);
            unsigned short* dst = which==0 ? wa1t : (which==1 ? wa2t : wc1t);
            int ci = idx & 63; int t = idx >> 6; int co = t & 63; int k = t >> 6;
            dst[idx] = f2bf(src[(co*64+ci)*27 + k]);
        }
    } else if (b < 1376){               // M_i = W1 + W2@W1 -> bf16 (80 blocks)
        int idx = (b-1296)*256 + tid;
        int i = idx >> 12; int r = idx & 4095;
        int co = r >> 6; int ci = r & 63;
        const float* W1 = w1s + i*4096;
        const float* W2 = w2s + i*4096;
        float m = W1[co*64+ci];
        for (int k=0;k<64;++k) m += W2[co*64+k]*W1[k*64+ci];
        Mt[idx] = f2bf(m);
    } else if (b < 1392){               // nin bf16 (16 blocks)
        int idx = (b-1376)*256 + tid;
        nint[idx] = f2bf(wnin[idx]);
    } else if (b < 1400){               // head taps [32][64] bf16 (8 blocks)
        int idx = (b-1392)*256 + tid;
        int co = idx & 63; int row = idx >> 6;
        float v = (row < 27) ? wc2[co*27 + row] : 0.f;
        wt2[row*64 + co] = f2bf(v);
    } else {                            // pool-conv weight transpose x3 (48 blocks)
        int bb = b - 1400;
        int which = bb/16;
        int idx = (bb - which*16)*256 + tid;
        const float* src = which==0 ? wp1 : (which==1 ? wp2 : wp3);
        int ci = idx >> 6; int co = idx & 63;
        wpt[which*4096 + idx] = src[co*64+ci];
    }
}

// ============ zero the pad columns (w=-1, w=128) of both padded volumes ============
__global__ __launch_bounds__(256) void k_zeropad(unsigned short* __restrict__ pv0,
                                                 unsigned short* __restrict__ pv1){
    int idx = blockIdx.x*256 + threadIdx.x;      // 98,304 = 12,288 seg x 8 parts
    int seg = idx >> 3, part = idx & 7;
    int vol = seg / 6144; int r2 = seg - vol*6144;
    int row = r2 >> 1; int col = (r2 & 1) ? 129 : 0;
    long boff = ((long)row*130 + col)*128 + part*16;
    u32x4v z = {0,0,0,0};
    char* base = (char*)(vol ? pv1 : pv0);
    *(u32x4v*)(base + boff) = z;
}

// ============ fvl [64][VOL] fp32 -> padded [PVOL][64] bf16 (LDS transpose) ============
__global__ __launch_bounds__(256) void k_tobf16v(const float* __restrict__ src,
                                                 unsigned short* __restrict__ dst){
    __shared__ unsigned short lds[64*66];
    int tid = threadIdx.x;
    long vbase = (long)blockIdx.x*64;
    int d = (int)(vbase >> 13);
    int h = (int)((vbase >> 7) & 63);
    int w0 = (int)(vbase & 127);
    long pbase = ((long)(d*64+h)*PW + w0 + 1);
    int v = tid & 63;
    int cg = tid >> 6;
#pragma unroll
    for (int k=0;k<16;++k){
        int ci = cg*16 + k;
        lds[v*66 + ci] = f2bf(src[(long)ci*VOL + vbase + v]);
    }
    __syncthreads();
#pragma unroll
    for (int it=0; it<2; ++it){
        int chunk = it*256 + tid;
        int vv = chunk >> 3, gp = chunk & 7;
        const unsigned short* s = lds + vv*66 + gp*8;
        unsigned int w0_ = (unsigned)s[0] | ((unsigned)s[1]<<16);
        unsigned int w1_ = (unsigned)s[2] | ((unsigned)s[3]<<16);
        unsigned int w2_ = (unsigned)s[4] | ((unsigned)s[5]<<16);
        unsigned int w3_ = (unsigned)s[6] | ((unsigned)s[7]<<16);
        u32x4v q = {w0_,w1_,w2_,w3_};
        *(u32x4v*)(dst + (pbase+vv)*64 + gp*8) = q;
    }
}

// ============ MFMA conv3x3x3: B LDS-staged, A (weights) direct from L2 ============
// Weights are L2-resident (221KB total, read by all blocks) -> no LDS staging
// needed; drops LDS 70KB->33KB (2->3 blocks/CU) and halves per-stage drain.
template<bool AUX, bool RELU>
__global__ __launch_bounds__(256,3) void k_conv3m(
    const unsigned short* __restrict__ in, const unsigned short* __restrict__ wt,
    const unsigned short* __restrict__ aux, const unsigned short* __restrict__ auxw,
    unsigned short* __restrict__ out)
{
    __shared__ __align__(16) char sB[33280];

    const int tid  = threadIdx.x;
    const int lane = tid & 63;
    const int wave = tid >> 6;
    const int ll = lane & 15;
    const int kg = lane >> 4;
    const int bid = blockIdx.x;
    const int wid = ((bid & 7) * 192) + (bid >> 3);
    const int vbr = wid*256;
    const int d  = vbr >> 13;
    const int h0 = (vbr >> 7) & 63;
    const int my_h  = h0 + (wave >> 1);
    const int my_w0 = (wave & 1) * 64;
    const long pvb = (long)(d*64 + my_h)*PW + my_w0 + 1;

    const char* inb = (const char*)in;

    f32x4 acc[4][4];
#pragma unroll
    for (int a=0;a<4;++a)
#pragma unroll
        for (int b=0;b<4;++b) acc[a][b] = (f32x4){0.f,0.f,0.f,0.f};

#pragma unroll
    for (int kd=0; kd<3; ++kd){
        const int dd = d + kd - 1;
        if ((unsigned)dd >= 48u) continue;
        const long rowstart = ((long)(dd*64 + h0 - 1)) * 130;
#pragma unroll
        for (int khalf=0; khalf<2; ++khalf){
            __syncthreads();
#pragma unroll
            for (int rnd=0; rnd<8; ++rnd){
                int j = rnd*4096 + tid*16;
                int q = j ^ (((j>>7)&3)<<4);
                const char* src = inb + (rowstart + (q>>6))*128 + khalf*64 + (q&63);
                gload16(src, sB + j);
            }
            if (tid < 32){
                int j = 32768 + tid*16;
                int q = j ^ (((j>>7)&3)<<4);
                const char* src = inb + (rowstart + (q>>6))*128 + khalf*64 + (q&63);
                gload16(src, sB + j);
            }
            __syncthreads();
#pragma unroll
            for (int kh=0; kh<3; ++kh){
                const int hh = my_h + kh - 1;
                if ((unsigned)hh >= 64u) continue;
                const int rr = (wave>>1) + kh;
#pragma unroll
                for (int kw=0; kw<3; ++kw){
                    const unsigned short* wk = wt + (long)((kd*3+kh)*3+kw)*4096
                                                  + khalf*32 + kg*8;
                    bf16x8 Af[4], Bf[4];
#pragma unroll
                    for (int t=0;t<4;++t)
                        Af[t] = *(const bf16x8*)(wk + (t*16+ll)*64);
#pragma unroll
                    for (int vt=0; vt<4; ++vt){
                        int vrel = rr*130 + my_w0 + vt*16 + ll + kw;
                        int qb = vrel*64 + kg*16;
                        Bf[vt] = *(const bf16x8*)(sB + (qb ^ (((qb>>7)&3)<<4)));
                    }
#pragma unroll
                    for (int vt=0; vt<4; ++vt)
#pragma unroll
                        for (int t=0; t<4; ++t)
                            acc[t][vt] = __builtin_amdgcn_mfma_f32_16x16x32_bf16(Af[t], Bf[vt], acc[t][vt], 0,0,0);
                }
            }
        }
    }

    if (AUX){
        bf16x8 Aa[2][4], Ba[2][4];
#pragma unroll
        for (int half=0; half<2; ++half){
            const int ko = half*32 + kg*8;
#pragma unroll
            for (int t=0;t<4;++t)
                Aa[half][t] = *(const bf16x8*)(auxw + (t*16+ll)*64 + ko);
#pragma unroll
            for (int vt=0; vt<4; ++vt)
                Ba[half][vt] = *(const bf16x8*)(aux + (pvb + vt*16 + ll)*64 + ko);
        }
#pragma unroll
        for (int half=0; half<2; ++half)
#pragma unroll
            for (int vt=0; vt<4; ++vt)
#pragma unroll
                for (int t=0;t<4;++t)
                    acc[t][vt] = __builtin_amdgcn_mfma_f32_16x16x32_bf16(Aa[half][t], Ba[half][vt], acc[t][vt], 0,0,0);
    }

#pragma unroll
    for (int vt=0; vt<4; ++vt){
        unsigned short* op = out + (pvb + vt*16 + ll)*64 + kg*4;
#pragma unroll
        for (int t=0;t<4;++t){
            float r0 = acc[t][vt][0], r1 = acc[t][vt][1], r2 = acc[t][vt][2], r3 = acc[t][vt][3];
            if (RELU){ r0=fmaxf(r0,0.f); r1=fmaxf(r1,0.f); r2=fmaxf(r2,0.f); r3=fmaxf(r3,0.f); }
            unsigned int lo = (unsigned)f2bf(r0) | ((unsigned)f2bf(r1)<<16);
            unsigned int hi = (unsigned)f2bf(r2) | ((unsigned)f2bf(r3)<<16);
            u32x2v q = {lo, hi};
            *(u32x2v*)(op + t*16) = q;
        }
    }
}

// ============ HEAD: conv3(x,wc1)+relu fused with tap-GEMM; A direct from L2 ============
__global__ __launch_bounds__(256,3) void k_conv3h(
    const unsigned short* __restrict__ in, const unsigned short* __restrict__ wt,
    const unsigned short* __restrict__ wt2, unsigned short* __restrict__ t)
{
    __shared__ __align__(16) char sB[33280];

    const int tid  = threadIdx.x;
    const int lane = tid & 63;
    const int wave = tid >> 6;
    const int ll = lane & 15;
    const int kg = lane >> 4;
    const int bid = blockIdx.x;
    const int wid = ((bid & 7) * 192) + (bid >> 3);
    const int vbr = wid*256;
    const int d  = vbr >> 13;
    const int h0 = (vbr >> 7) & 63;
    const int my_h  = h0 + (wave >> 1);
    const int my_w0 = (wave & 1) * 64;
    const long pvb = (long)(d*64 + my_h)*PW + my_w0 + 1;

    const char* inb = (const char*)in;

    f32x4 acc[4][4];
#pragma unroll
    for (int a=0;a<4;++a)
#pragma unroll
        for (int b=0;b<4;++b) acc[a][b] = (f32x4){0.f,0.f,0.f,0.f};

#pragma unroll
    for (int kd=0; kd<3; ++kd){
        const int dd = d + kd - 1;
        if ((unsigned)dd >= 48u) continue;
        const long rowstart = ((long)(dd*64 + h0 - 1)) * 130;
#pragma unroll
        for (int khalf=0; khalf<2; ++khalf){
            __syncthreads();
#pragma unroll
            for (int rnd=0; rnd<8; ++rnd){
                int j = rnd*4096 + tid*16;
                int q = j ^ (((j>>7)&3)<<4);
                const char* src = inb + (rowstart + (q>>6))*128 + khalf*64 + (q&63);
                gload16(src, sB + j);
            }
            if (tid < 32){
                int j = 32768 + tid*16;
                int q = j ^ (((j>>7)&3)<<4);
                const char* src = inb + (rowstart + (q>>6))*128 + khalf*64 + (q&63);
                gload16(src, sB + j);
            }
            __syncthreads();
#pragma unroll
            for (int kh=0; kh<3; ++kh){
                const int hh = my_h + kh - 1;
                if ((unsigned)hh >= 64u) continue;
                const int rr = (wave>>1) + kh;
#pragma unroll
                for (int kw=0; kw<3; ++kw){
                    const unsigned short* wk = wt + (long)((kd*3+kh)*3+kw)*4096
                                                  + khalf*32 + kg*8;
                    bf16x8 Af[4], Bf[4];
#pragma unroll
                    for (int tt=0;tt<4;++tt)
                        Af[tt] = *(const bf16x8*)(wk + (tt*16+ll)*64);
#pragma unroll
                    for (int vt=0; vt<4; ++vt){
                        int vrel = rr*130 + my_w0 + vt*16 + ll + kw;
                        int qb = vrel*64 + kg*16;
                        Bf[vt] = *(const bf16x8*)(sB + (qb ^ (((qb>>7)&3)<<4)));
                    }
#pragma unroll
                    for (int vt=0; vt<4; ++vt)
#pragma unroll
                        for (int tt=0; tt<4; ++tt)
                            acc[tt][vt] = __builtin_amdgcn_mfma_f32_16x16x32_bf16(Af[tt], Bf[vt], acc[tt][vt], 0,0,0);
                }
            }
        }
    }

    // --- fused tap-GEMM epilogue (per-wave tile reuses sB after barrier) ---
    __syncthreads();
    char* myL = sB + wave*8192;
#pragma unroll
    for (int vt=0; vt<4; ++vt){
        const int row = vt*16 + ll;
        const int sw = (row & 7) << 4;
#pragma unroll
        for (int tt=0;tt<4;++tt){
            float r0 = fmaxf(acc[tt][vt][0],0.f), r1 = fmaxf(acc[tt][vt][1],0.f);
            float r2 = fmaxf(acc[tt][vt][2],0.f), r3 = fmaxf(acc[tt][vt][3],0.f);
            unsigned int lo = (unsigned)f2bf(r0) | ((unsigned)f2bf(r1)<<16);
            unsigned int hi = (unsigned)f2bf(r2) | ((unsigned)f2bf(r3)<<16);
            u32x2v q = {lo, hi};
            int colb = kg*8 + tt*32;
            *(u32x2v*)(myL + row*128 + (colb ^ sw)) = q;
        }
    }
    f32x4 acc2[2][4];
#pragma unroll
    for (int a=0;a<2;++a)
#pragma unroll
        for (int b=0;b<4;++b) acc2[a][b] = (f32x4){0.f,0.f,0.f,0.f};
#pragma unroll
    for (int half=0; half<2; ++half){
        const int ko = half*32 + kg*8;
        bf16x8 afr[2];
#pragma unroll
        for (int tl=0;tl<2;++tl)
            afr[tl] = *(const bf16x8*)(wt2 + (tl*16+ll)*64 + ko);
#pragma unroll
        for (int vt=0; vt<4; ++vt){
            const int row = vt*16 + ll;
            const int sw = (row & 7) << 4;
            int colb = half*64 + kg*16;
            bf16x8 bfr = *(const bf16x8*)(myL + row*128 + (colb ^ sw));
#pragma unroll
            for (int tl=0;tl<2;++tl)
                acc2[tl][vt] = __builtin_amdgcn_mfma_f32_16x16x32_bf16(afr[tl], bfr, acc2[tl][vt], 0,0,0);
        }
    }
#pragma unroll
    for (int vt=0; vt<4; ++vt){
        long vx = pvb + vt*16 + ll;
#pragma unroll
        for (int tl=0;tl<2;++tl){
#pragma unroll
            for (int r=0;r<4;++r){
                int tap = tl*16 + kg*4 + r;
                if (tap < 27) t[(long)tap*PVOL + vx] = f2bf(acc2[tl][vt][r]);
            }
        }
    }
}

// ============ FUSED residual chain (R9, unchanged) ============
__global__ __launch_bounds__(256,3) void k_chain(const unsigned short* __restrict__ in,
        const unsigned short* __restrict__ Mt, unsigned short* __restrict__ out){
    __shared__ __align__(16) char sX[4][8192];
    const int lane = threadIdx.x & 63;
    const int wave = threadIdx.x >> 6;
    const int ll = lane & 15;
    const int kg = lane >> 4;
    const long vb = (long)blockIdx.x*256 + wave*64;
    char* myL = sX[wave];

    bf16x8 B[2][4];
#pragma unroll
    for (int half=0; half<2; ++half){
        const int ko = half*32 + kg*8;
#pragma unroll
        for (int vt=0; vt<4; ++vt)
            B[half][vt] = *(const bf16x8*)(in + (vb+vt*16+ll)*64 + ko);
    }

#pragma unroll
    for (int s=0; s<5; ++s){
        const unsigned short* wt = Mt + s*4096;
        bf16x8 A[2][4];
#pragma unroll
        for (int half=0; half<2; ++half){
            const int ko = half*32 + kg*8;
#pragma unroll
            for (int t=0;t<4;++t)
                A[half][t] = *(const bf16x8*)(wt + (t*16+ll)*64 + ko);
        }
        f32x4 acc[4][4];
#pragma unroll
        for (int a=0;a<4;++a)
#pragma unroll
            for (int b=0;b<4;++b) acc[a][b] = (f32x4){0.f,0.f,0.f,0.f};
#pragma unroll
        for (int half=0; half<2; ++half)
#pragma unroll
            for (int vt=0; vt<4; ++vt)
#pragma unroll
                for (int t=0;t<4;++t)
                    acc[t][vt] = __builtin_amdgcn_mfma_f32_16x16x32_bf16(A[half][t], B[half][vt], acc[t][vt], 0,0,0);

        if (s < 4){
#pragma unroll
            for (int vt=0; vt<4; ++vt){
                const int row = vt*16 + ll;
                const int sw = (row & 7) << 4;
#pragma unroll
                for (int t=0;t<4;++t){
                    float r0 = fmaxf(acc[t][vt][0],0.f), r1 = fmaxf(acc[t][vt][1],0.f);
                    float r2 = fmaxf(acc[t][vt][2],0.f), r3 = fmaxf(acc[t][vt][3],0.f);
                    unsigned int lo = (unsigned)f2bf(r0) | ((unsigned)f2bf(r1)<<16);
                    unsigned int hi = (unsigned)f2bf(r2) | ((unsigned)f2bf(r3)<<16);
                    u32x2v q = {lo, hi};
                    int colb = kg*8 + t*32;
                    *(u32x2v*)(myL + row*128 + (colb ^ sw)) = q;
                }
            }
#pragma unroll
            for (int half=0; half<2; ++half){
#pragma unroll
                for (int vt=0; vt<4; ++vt){
                    const int row = vt*16 + ll;
                    const int sw = (row & 7) << 4;
                    int colb = half*64 + kg*16;
                    B[half][vt] = *(const bf16x8*)(myL + row*128 + (colb ^ sw));
                }
            }
        } else {
#pragma unroll
            for (int vt=0; vt<4; ++vt){
                unsigned short* op = out + (vb+vt*16+ll)*64 + kg*4;
#pragma unroll
                for (int t=0;t<4;++t){
                    float r0 = fmaxf(acc[t][vt][0],0.f), r1 = fmaxf(acc[t][vt][1],0.f);
                    float r2 = fmaxf(acc[t][vt][2],0.f), r3 = fmaxf(acc[t][vt][3],0.f);
                    unsigned int lo = (unsigned)f2bf(r0) | ((unsigned)f2bf(r1)<<16);
                    unsigned int hi = (unsigned)f2bf(r2) | ((unsigned)f2bf(r3)<<16);
                    u32x2v q = {lo, hi};
                    *(u32x2v*)(op + t*16) = q;
                }
            }
        }
    }
}

// ============ head stage 2: 4 voxels/thread (R14, unchanged) ============
__global__ __launch_bounds__(256) void k_heads(const unsigned short* __restrict__ t,
        const float* __restrict__ bias, float* __restrict__ out){
    int g = blockIdx.x*256 + threadIdx.x;
    int v0 = g*4;
    int w0 = v0 & 127; int h = (v0>>7)&63; int d = v0>>13;
    long p0 = (long)(d*64+h)*PW + w0 + 1;
    float b0 = bias[0];
    float s0=b0, s1=b0, s2=b0, s3=b0;
#pragma unroll
    for (int kd=0;kd<3;++kd){
#pragma unroll
      for (int kh=0;kh<3;++kh){
#pragma unroll
        for (int kw=0;kw<3;++kw){
            const int tap = (kd*3+kh)*3+kw;
            const long dvp = (long)((kd-1)*64 + (kh-1))*PW + (kw-1);
            bool okdh = ((unsigned)(d+kd-1)<48u) && ((unsigned)(h+kh-1)<64u);
            const unsigned short* tp = t + (long)tap*PVOL;
            bool ok0 = okdh && ((unsigned)(w0+0+kw-1)<128u);
            bool ok1 = okdh && ((unsigned)(w0+1+kw-1)<128u);
            bool ok2 = okdh && ((unsigned)(w0+2+kw-1)<128u);
            bool ok3 = okdh && ((unsigned)(w0+3+kw-1)<128u);
            long a0 = ok0 ? (p0+0+dvp) : p0;
            long a1 = ok1 ? (p0+1+dvp) : p0;
            long a2 = ok2 ? (p0+2+dvp) : p0;
            long a3 = ok3 ? (p0+3+dvp) : p0;
            float x0 = bf2f(tp[a0]);
            float x1 = bf2f(tp[a1]);
            float x2 = bf2f(tp[a2]);
            float x3 = bf2f(tp[a3]);
            s0 += ok0 ? x0 : 0.f;
            s1 += ok1 ? x1 : 0.f;
            s2 += ok2 ? x2 : 0.f;
            s3 += ok3 ? x3 : 0.f;
        }
      }
    }
    f32x4 r = {s0,s1,s2,s3};
    *(f32x4*)(out + v0) = r;
}

// ============ pool stage 1: S3 cell sums (unchanged) ============
__global__ __launch_bounds__(256) void k_pool3(const unsigned short* __restrict__ in,
                                               float* __restrict__ S3){
    __shared__ float sm[32*68];
    int tid = threadIdx.x;
    int cg = tid & 7, part = tid >> 3;
    int cell = blockIdx.x;
    int Z = cell >> 8, Y = (cell >> 4) & 15, X = cell & 15;
    float a[8];
#pragma unroll
    for (int j=0;j<8;++j) a[j]=0.f;
#pragma unroll
    for (int j=0;j<3;++j){
        int i = part*3 + j;
        int di = i >> 5, rem = i & 31, hi = rem >> 3, wi = rem & 7;
        long p = ((long)((3*Z+di)*64 + 4*Y+hi))*PW + 8*X+wi + 1;
        u32x4v q = *(const u32x4v*)(in + p*64 + cg*8);
#pragma unroll
        for (int e=0;e<4;++e){ a[e*2] += bflo(q[e]); a[e*2+1] += bfhi(q[e]); }
    }
#pragma unroll
    for (int j=0;j<8;++j) sm[part*68 + cg*8 + j] = a[j];
    __syncthreads();
    if (tid < 64){
        float s=0.f;
        for (int r=0;r<32;++r) s += sm[r*68 + tid];
        S3[tid*4096 + cell] = s;
    }
}

// ============ p2 sums from S3 (unchanged) ============
__global__ __launch_bounds__(256) void k_pool2(const float* __restrict__ S3,
                                               float* __restrict__ P2){
    int idx = blockIdx.x*256 + threadIdx.x;
    int cell = idx & 511; int c = idx >> 9;
    int z = cell >> 6, y = (cell >> 3) & 7, x = cell & 7;
    const float* b = S3 + c*4096;
    float s = 0.f;
#pragma unroll
    for (int a2=0;a2<2;++a2)
#pragma unroll
        for (int b2=0;b2<2;++b2)
#pragma unroll
            for (int e=0;e<2;++e)
                s += b[((2*z+a2)<<8) + ((2*y+b2)<<4) + (2*x+e)];
    P2[c*512 + cell] = s;
}

// ============ g + gc from S3 (unchanged) ============
__global__ void k_gcm(const float* __restrict__ S3, const float* __restrict__ wp0,
                      float* __restrict__ gc){
    __shared__ float sm[4][64];
    __shared__ float sg[64];
    int tid = threadIdx.x;
    int c = tid & 63, part = tid >> 6;
    float s = 0.f;
    const float* row = S3 + c*4096 + part*1024;
    for (int i=0;i<1024;i+=4){
        f32x4 q = *(const f32x4*)(row + i);
        s += q[0]+q[1]+q[2]+q[3];
    }
    sm[part][c] = s;
    __syncthreads();
    if (tid < 64){
        sg[tid] = (sm[0][tid]+sm[1][tid]+sm[2][tid]+sm[3][tid]) * (1.0f/(float)VOL);
    }
    __syncthreads();
    if (tid < 64){
        float g=0.f;
        for (int ci=0;ci<64;++ci) g += wp0[tid*64+ci]*sg[ci];
        gc[tid] = g;
    }
}

// ============ p4 sums (unchanged) ============
__global__ __launch_bounds__(256) void k_pool4(const unsigned short* __restrict__ in,
                                               float* __restrict__ P4){
    __shared__ float sm[32*68];
    int tid = threadIdx.x;
    int cg = tid & 7, part = (tid >> 3) & 3, slot = tid >> 5;
    int cell = blockIdx.x*8 + slot;
    int z = cell / 800; int rem = cell - z*800; int y = rem / 25; int x = rem - y*25;
    int a2 = part >> 1, b2 = part & 1;
    float a[8];
#pragma unroll
    for (int j=0;j<8;++j) a[j]=0.f;
#pragma unroll
    for (int e=0;e<5;++e){
        long p = ((long)((2*z+a2)*64 + 2*y+b2))*PW + 5*x+e + 1;
        u32x4v q = *(const u32x4v*)(in + p*64 + cg*8);
#pragma unroll
        for (int k=0;k<4;++k){ a[k*2] += bflo(q[k]); a[k*2+1] += bfhi(q[k]); }
    }
#pragma unroll
    for (int j=0;j<8;++j) sm[(slot*4+part)*68 + cg*8 + j] = a[j];
    __syncthreads();
#pragma unroll
    for (int r=0;r<2;++r){
        int o = r*256 + tid;
        int c = o >> 3, s = o & 7;
        float v = sm[(s*4+0)*68 + c] + sm[(s*4+1)*68 + c]
                + sm[(s*4+2)*68 + c] + sm[(s*4+3)*68 + c];
        P4[(long)c*19200 + blockIdx.x*8 + s] = v;
    }
}

// ============ 1x1 conv fp32 on pooled SUMS (unchanged) ============
__global__ void k_conv1(const float* __restrict__ in, const float* __restrict__ wt,
                        float* __restrict__ out, int vol, float scale){
    int v = blockIdx.x*256 + threadIdx.x;
    if (v >= vol) return;
    float acc[64];
#pragma unroll
    for (int i=0;i<64;++i) acc[i]=0.f;
    for (int ci=0; ci<64; ++ci){
        float xv = in[ci*vol + v];
        const float* wr = wt + ci*64;
#pragma unroll
        for (int co=0; co<64; ++co) acc[co] = fmaf(wr[co], xv, acc[co]);
    }
    float* op = out + (long)v*64;
#pragma unroll
    for (int q=0;q<16;++q){
        f32x4 t = {acc[q*4]*scale, acc[q*4+1]*scale, acc[q*4+2]*scale, acc[q*4+3]*scale};
        *(f32x4*)(op + q*4) = t;
    }
}

// ============ trilinear gather ============
__device__ __forceinline__ void tri_setup(int d,int h,int w,int gd,int gh,int gw,
                                          int* o, float* wt){
    float fz = (d+0.5f)*((float)gd/(float)DD) - 0.5f;
    float fy = (h+0.5f)*((float)gh/(float)HH) - 0.5f;
    float fx = (w+0.5f)*((float)gw/(float)WW) - 0.5f;
    float z0f = floorf(fz), y0f = floorf(fy), x0f = floorf(fx);
    float tz = fz - z0f, ty = fy - y0f, tx = fx - x0f;
    int z0 = (int)z0f, y0 = (int)y0f, x0 = (int)x0f;
    int z1 = z0+1, y1 = y0+1, x1 = x0+1;
    z0 = min(max(z0,0),gd-1); z1 = min(max(z1,0),gd-1);
    y0 = min(max(y0,0),gh-1); y1 = min(max(y1,0),gh-1);
    x0 = min(max(x0,0),gw-1); x1 = min(max(x1,0),gw-1);
    o[0] = (z0*gh+y0)*gw+x0; wt[0] = (1-tz)*(1-ty)*(1-tx);
    o[1] = (z0*gh+y0)*gw+x1; wt[1] = (1-tz)*(1-ty)*tx;
    o[2] = (z0*gh+y1)*gw+x0; wt[2] = (1-tz)*ty*(1-tx);
    o[3] = (z0*gh+y1)*gw+x1; wt[3] = (1-tz)*ty*tx;
    o[4] = (z1*gh+y0)*gw+x0; wt[4] = tz*(1-ty)*(1-tx);
    o[5] = (z1*gh+y0)*gw+x1; wt[5] = tz*(1-ty)*tx;
    o[6] = (z1*gh+y1)*gw+x0; wt[6] = tz*ty*(1-tx);
    o[7] = (z1*gh+y1)*gw+x1; wt[7] = tz*ty*tx;
}

// out = relu((xc + 0.25*(gc + up(p2)+up(p3)+up(p4)))/2)
// R13/R14 proven fused form: 256-thread full-voxel blocks, XCD swizzle,
// nt fp32 stores + voxel-major bf16 store. (R15 split was a regression.)
__global__ __launch_bounds__(256) void k_combine(
        const unsigned short* __restrict__ xc, const float* __restrict__ gc,
        const float* __restrict__ p2, const float* __restrict__ p3,
        const float* __restrict__ p4, float* __restrict__ xout,
        unsigned short* __restrict__ xv){
    int tid = threadIdx.x;
    const int bid = blockIdx.x;
    const int wid = ((bid & 7) * 192) + (bid >> 3);   // 1536 blocks, bijective
    long v = (long)wid*256 + tid;
    int w = v & 127; int h = (v>>7)&63; int d = v>>13;
    long p = (long)(d*64+h)*PW + w + 1;
    int o2[8], o3[8], o4[8];
    float w2_[8], w3_[8], w4_[8];
    tri_setup(d,h,w, 8,8,8,    o2, w2_);
    tri_setup(d,h,w, 16,16,16, o3, w3_);
    tri_setup(d,h,w, 24,32,25, o4, w4_);
#pragma unroll
    for (int half=0; half<2; ++half){
        float res[32];
#pragma unroll
        for (int j=0;j<32;++j) res[j] = gc[half*32+j];
#pragma unroll
        for (int t=0;t<8;++t){
            const float* b2 = p2 + (long)o2[t]*64 + half*32;
#pragma unroll
            for (int q=0;q<8;++q){
                f32x4 x4 = *(const f32x4*)(b2 + q*4);
                res[q*4+0] = fmaf(w2_[t], x4[0], res[q*4+0]);
                res[q*4+1] = fmaf(w2_[t], x4[1], res[q*4+1]);
                res[q*4+2] = fmaf(w2_[t], x4[2], res[q*4+2]);
                res[q*4+3] = fmaf(w2_[t], x4[3], res[q*4+3]);
            }
        }
#pragma unroll
        for (int t=0;t<8;++t){
            const float* b3 = p3 + (long)o3[t]*64 + half*32;
#pragma unroll
            for (int q=0;q<8;++q){
                f32x4 x4 = *(const f32x4*)(b3 + q*4);
                res[q*4+0] = fmaf(w3_[t], x4[0], res[q*4+0]);
                res[q*4+1] = fmaf(w3_[t], x4[1], res[q*4+1]);
                res[q*4+2] = fmaf(w3_[t], x4[2], res[q*4+2]);
                res[q*4+3] = fmaf(w3_[t], x4[3], res[q*4+3]);
            }
        }
#pragma unroll
        for (int t=0;t<8;++t){
            const float* b4 = p4 + (long)o4[t]*64 + half*32;
#pragma unroll
            for (int q=0;q<8;++q){
                f32x4 x4 = *(const f32x4*)(b4 + q*4);
                res[q*4+0] = fmaf(w4_[t], x4[0], res[q*4+0]);
                res[q*4+1] = fmaf(w4_[t], x4[1], res[q*4+1]);
                res[q*4+2] = fmaf(w4_[t], x4[2], res[q*4+2]);
                res[q*4+3] = fmaf(w4_[t], x4[3], res[q*4+3]);
            }
        }
        const u32x4v* xq = (const u32x4v*)(xc + p*64 + half*32);
#pragma unroll
        for (int q=0;q<4;++q){
            u32x4v qv = xq[q];
            unsigned int pk[4];
#pragma unroll
            for (int e=0;e<4;++e){
                int j = q*8 + e*2;
                float r0 = fmaxf((bflo(qv[e]) + 0.25f*res[j])*0.5f, 0.f);
                float r1 = fmaxf((bfhi(qv[e]) + 0.25f*res[j+1])*0.5f, 0.f);
                __builtin_nontemporal_store(r0, &xout[(long)(half*32+j)*VOL + v]);
                __builtin_nontemporal_store(r1, &xout[(long)(half*32+j+1)*VOL + v]);
                pk[e] = (unsigned)f2bf(r0) | ((unsigned)f2bf(r1)<<16);
            }
            u32x4v pq = {pk[0],pk[1],pk[2],pk[3]};
            *(u32x4v*)(xv + p*64 + half*32 + q*8) = pq;
        }
    }
}

// ================= workspace layout (bytes) =================
constexpr long RPV = GUARD + PVBYTES + GUARD;
constexpr long OFF_PV0R = 0;
constexpr long OFF_PV1R = RPV;
constexpr long OFF_WA1 = 2*RPV;
constexpr long OFF_WA2 = OFF_WA1 + 221184;
constexpr long OFF_WC1 = OFF_WA2 + 221184;
constexpr long OFF_NIN = OFF_WC1 + 221184;
constexpr long OFF_MT  = OFF_NIN + 8192;
constexpr long OFF_WT2 = OFF_MT + 40960;
constexpr long OFF_WPT = OFF_WT2 + 4096;
constexpr long OFF_GC  = OFF_WPT + 49152;
constexpr long OFF_P2  = OFF_GC + 256;
constexpr long OFF_P2C = OFF_P2 + 131072;
constexpr long OFF_S3  = OFF_P2C + 131072;
constexpr long OFF_P3C = OFF_S3 + 1048576;
constexpr long OFF_P4  = OFF_P3C + 1048576;
constexpr long OFF_P4C = OFF_P4 + 4915200;
// end ~= 115.4 MB

extern "C" void kernel_launch(void* const* d_in, const int* in_sizes, int n_in,
                              void* d_out, int out_size, void* d_ws, size_t ws_size,
                              hipStream_t stream) {
    const float* fvl  = (const float*)d_in[0];
    const float* w_a1 = (const float*)d_in[1];
    const float* w_a2 = (const float*)d_in[2];
    const float* wnin = (const float*)d_in[3];
    const float* w1s  = (const float*)d_in[4];
    const float* w2s  = (const float*)d_in[5];
    const float* wp0  = (const float*)d_in[6];
    const float* wp1  = (const float*)d_in[7];
    const float* wp2  = (const float*)d_in[8];
    const float* wp3  = (const float*)d_in[9];
    const float* wc1  = (const float*)d_in[10];
    const float* wc2  = (const float*)d_in[11];
    const float* bc   = (const float*)d_in[12];

    char* ws = (char*)d_ws;
    unsigned short* PV0  = (unsigned short*)(ws + OFF_PV0R + GUARD);
    unsigned short* PV1  = (unsigned short*)(ws + OFF_PV1R + GUARD);
    unsigned short* wa1t = (unsigned short*)(ws + OFF_WA1);
    unsigned short* wa2t = (unsigned short*)(ws + OFF_WA2);
    unsigned short* wc1t = (unsigned short*)(ws + OFF_WC1);
    unsigned short* nint = (unsigned short*)(ws + OFF_NIN);
    unsigned short* Mt   = (unsigned short*)(ws + OFF_MT);
    unsigned short* wt2  = (unsigned short*)(ws + OFF_WT2);
    float* wpt  = (float*)(ws + OFF_WPT);
    float* gc   = (float*)(ws + OFF_GC);
    float* p2   = (float*)(ws + OFF_P2);
    float* p2c  = (float*)(ws + OFF_P2C);
    float* S3   = (float*)(ws + OFF_S3);
    float* p3c  = (float*)(ws + OFF_P3C);
    float* p4   = (float*)(ws + OFF_P4);
    float* p4c  = (float*)(ws + OFF_P4C);

    float* Xout = (float*)d_out;
    float* Cout = Xout + (long)NC*VOL;
    unsigned short* Tbuf = PV1;     // head t bf16 [27][PVOL], reuses PV1 (free after combine)

    const int GBR = VOL/256;     // 1536
    const int GBP = PVOL/256;    // 1560

    // zero only the pad columns (1.5MB instead of 102MB of memset)
    k_zeropad<<<384,256,0,stream>>>(PV0, PV1);

    // all weight prep in ONE launch
    k_prep_all<<<1448,256,0,stream>>>(w_a1, w_a2, wc1, wnin, wc2, w1s, w2s,
                                      wp1, wp2, wp3,
                                      wa1t, wa2t, wc1t, nint, wt2, Mt, wpt);
    k_tobf16v<<<VOL/64,256,0,stream>>>(fvl, PV0);

    // stage A/B: conv3 chain
    k_conv3m<false,false><<<GBR,256,0,stream>>>(PV0, wa1t, nullptr, nullptr, PV1);
    k_conv3m<true,false><<<GBR,256,0,stream>>>(PV1, wa2t, PV0, nint, PV0);

    // stage C: fused 5-stage residual chain PV0 -> PV1 (one kernel)
    k_chain<<<GBP,256,0,stream>>>(PV0, Mt, PV1);

    // stage D: pool pyramid
    k_pool3<<<4096,256,0,stream>>>(PV1, S3);
    k_gcm<<<1,256,0,stream>>>(S3, wp0, gc);
    k_pool2<<<128,256,0,stream>>>(S3, p2);
    k_pool4<<<2400,256,0,stream>>>(PV1, p4);
    k_conv1<<<2,256,0,stream>>>(p2, wpt + 0*4096, p2c, 512,   1.0f/768.0f);
    k_conv1<<<16,256,0,stream>>>(S3, wpt + 1*4096, p3c, 4096, 1.0f/96.0f);
    k_conv1<<<75,256,0,stream>>>(p4, wpt + 2*4096, p4c, 19200, 1.0f/20.0f);

    // combine (fused, proven): Xout fp32 + padded bf16 x into PV0
    k_combine<<<GBR,256,0,stream>>>(PV1, gc, p2c, p3c, p4c, Xout, PV0);

    // head: conv3(x,wc1)+relu fused with tap-GEMM -> Tbuf (PV1); then gather-sum
    k_conv3h<<<GBR,256,0,stream>>>(PV0, wc1t, wt2, Tbuf);
    k_heads<<<384,256,0,stream>>>(Tbuf, bc, Cout);
}

// Round 18
// 583.194 us; speedup vs baseline: 1.5095x; 1.4399x over previous
//
#include <hip/hip_runtime.h>
#include <math.h>

#define DD 48
#define HH 64
#define WW 128
#define VOL (DD*HH*WW)     // 393216 real voxels
#define PW 130             // padded W
#define PROWS (DD*HH)      // 3072 rows
#define PVOL (PROWS*PW)    // 399360 padded voxels
#define PVBYTES ((long)PVOL*64*2) // 51,118,080 bytes per padded bf16 volume
#define GUARD 16640L       // one padded row guard each side
#define NC 64

typedef __attribute__((ext_vector_type(8))) short bf16x8;
typedef __attribute__((ext_vector_type(4))) float f32x4;
typedef __attribute__((ext_vector_type(4))) unsigned int u32x4v;
typedef __attribute__((ext_vector_type(2))) unsigned int u32x2v;

__device__ __forceinline__ float bflo(unsigned int u){
    union { unsigned int i; float f; } x; x.i = u<<16; return x.f; }
__device__ __forceinline__ float bfhi(unsigned int u){
    union { unsigned int i; float f; } x; x.i = u & 0xffff0000u; return x.f; }
__device__ __forceinline__ float bf2f(unsigned short u){
    union { unsigned int i; float f; } x; x.i = ((unsigned int)u)<<16; return x.f; }
__device__ __forceinline__ unsigned short f2bf(float f){
    union { float f; unsigned int i; } x; x.f = f;
    unsigned int i = x.i;
    return (unsigned short)((i + 0x7fffu + ((i>>16)&1u)) >> 16);  // RNE
}

__device__ __forceinline__ void gload16(const void* g, void* l){
    __builtin_amdgcn_global_load_lds(
        (const __attribute__((address_space(1))) void*)g,
        (__attribute__((address_space(3))) void*)l, 16, 0, 0);
}

// ================= merged weight prep (one launch) =================
__global__ void k_prep_all(
    const float* __restrict__ w_a1, const float* __restrict__ w_a2,
    const float* __restrict__ wc1,  const float* __restrict__ wnin,
    const float* __restrict__ wc2,  const float* __restrict__ w1s,
    const float* __restrict__ w2s,  const float* __restrict__ wp1,
    const float* __restrict__ wp2,  const float* __restrict__ wp3,
    unsigned short* __restrict__ wa1t, unsigned short* __restrict__ wa2t,
    unsigned short* __restrict__ wc1t, unsigned short* __restrict__ nint,
    unsigned short* __restrict__ wt2,  unsigned short* __restrict__ Mt,
    float* __restrict__ wpt)
{
    int b = blockIdx.x, tid = threadIdx.x;
    if (b < 1296){                      // [k=27][co][ci] bf16 repack x3 (432 blocks each)
        int which = b/432, bb = b - which*432;
        int idx = bb*256 + tid;
        if (idx < 27*64*64){
            const float* src = which==0 ? w_a1 : (which==1 ? w_a2 : wc1);
            unsigned short* dst = which==0 ? wa1t : (which==1 ? wa2t : wc1t);
            int ci = idx & 63; int t = idx >> 6; int co = t & 63; int k = t >> 6;
            dst[idx] = f2bf(src[(co*64+ci)*27 + k]);
        }
    } else if (b < 1376){               // M_i = W1 + W2@W1 -> bf16 (80 blocks)
        int idx = (b-1296)*256 + tid;
        int i = idx >> 12; int r = idx & 4095;
        int co = r >> 6; int ci = r & 63;
        const float* W1 = w1s + i*4096;
        const float* W2 = w2s + i*4096;
        float m = W1[co*64+ci];
        for (int k=0;k<64;++k) m += W2[co*64+k]*W1[k*64+ci];
        Mt[idx] = f2bf(m);
    } else if (b < 1392){               // nin bf16 (16 blocks)
        int idx = (b-1376)*256 + tid;
        nint[idx] = f2bf(wnin[idx]);
    } else if (b < 1400){               // head taps [32][64] bf16 (8 blocks)
        int idx = (b-1392)*256 + tid;
        int co = idx & 63; int row = idx >> 6;
        float v = (row < 27) ? wc2[co*27 + row] : 0.f;
        wt2[row*64 + co] = f2bf(v);
    } else {                            // pool-conv weight transpose x3 (48 blocks)
        int bb = b - 1400;
        int which = bb/16;
        int idx = (bb - which*16)*256 + tid;
        const float* src = which==0 ? wp1 : (which==1 ? wp2 : wp3);
        int ci = idx >> 6; int co = idx & 63;
        wpt[which*4096 + idx] = src[co*64+ci];
    }
}

// ============ zero the pad columns (w=-1, w=128) of both padded volumes ============
__global__ __launch_bounds__(256) void k_zeropad(unsigned short* __restrict__ pv0,
                                                 unsigned short* __restrict__ pv1){
    int idx = blockIdx.x*256 + threadIdx.x;      // 98,304 = 12,288 seg x 8 parts
    int seg = idx >> 3, part = idx & 7;
    int vol = seg / 6144; int r2 = seg - vol*6144;
    int row = r2 >> 1; int col = (r2 & 1) ? 129 : 0;
    long boff = ((long)row*130 + col)*128 + part*16;
    u32x4v z = {0,0,0,0};
    char* base = (char*)(vol ? pv1 : pv0);
    *(u32x4v*)(base + boff) = z;
}

// ============ fvl [64][VOL] fp32 -> padded [PVOL][64] bf16 (LDS transpose) ============
__global__ __launch_bounds__(256) void k_tobf16v(const float* __restrict__ src,
                                                 unsigned short* __restrict__ dst){
    __shared__ unsigned short lds[64*66];
    int tid = threadIdx.x;
    long vbase = (long)blockIdx.x*64;
    int d = (int)(vbase >> 13);
    int h = (int)((vbase >> 7) & 63);
    int w0 = (int)(vbase & 127);
    long pbase = ((long)(d*64+h)*PW + w0 + 1);
    int v = tid & 63;
    int cg = tid >> 6;
#pragma unroll
    for (int k=0;k<16;++k){
        int ci = cg*16 + k;
        lds[v*66 + ci] = f2bf(src[(long)ci*VOL + vbase + v]);
    }
    __syncthreads();
#pragma unroll
    for (int it=0; it<2; ++it){
        int chunk = it*256 + tid;
        int vv = chunk >> 3, gp = chunk & 7;
        const unsigned short* s = lds + vv*66 + gp*8;
        unsigned int w0_ = (unsigned)s[0] | ((unsigned)s[1]<<16);
        unsigned int w1_ = (unsigned)s[2] | ((unsigned)s[3]<<16);
        unsigned int w2_ = (unsigned)s[4] | ((unsigned)s[5]<<16);
        unsigned int w3_ = (unsigned)s[6] | ((unsigned)s[7]<<16);
        u32x4v q = {w0_,w1_,w2_,w3_};
        *(u32x4v*)(dst + (pbase+vv)*64 + gp*8) = q;
    }
}

// ============ MFMA conv3x3x3: A+B LDS-staged via global_load_lds (R13 proven) ============
template<bool AUX, bool RELU>
__global__ __launch_bounds__(256,2) void k_conv3m(
    const unsigned short* __restrict__ in, const unsigned short* __restrict__ wt,
    const unsigned short* __restrict__ aux, const unsigned short* __restrict__ auxw,
    unsigned short* __restrict__ out)
{
    __shared__ __align__(16) char sA[36864];
    __shared__ __align__(16) char sB[33280];

    const int tid  = threadIdx.x;
    const int lane = tid & 63;
    const int wave = tid >> 6;
    const int ll = lane & 15;
    const int kg = lane >> 4;
    const int bid = blockIdx.x;
    const int wid = ((bid & 7) * 192) + (bid >> 3);
    const int vbr = wid*256;
    const int d  = vbr >> 13;
    const int h0 = (vbr >> 7) & 63;
    const int my_h  = h0 + (wave >> 1);
    const int my_w0 = (wave & 1) * 64;
    const long pvb = (long)(d*64 + my_h)*PW + my_w0 + 1;

    const char* inb = (const char*)in;
    const char* wtb = (const char*)wt;

    f32x4 acc[4][4];
#pragma unroll
    for (int a=0;a<4;++a)
#pragma unroll
        for (int b=0;b<4;++b) acc[a][b] = (f32x4){0.f,0.f,0.f,0.f};

#pragma unroll
    for (int kd=0; kd<3; ++kd){
        const int dd = d + kd - 1;
        if ((unsigned)dd >= 48u) continue;
        const long rowstart = ((long)(dd*64 + h0 - 1)) * 130;
#pragma unroll
        for (int khalf=0; khalf<2; ++khalf){
            __syncthreads();
#pragma unroll
            for (int rnd=0; rnd<9; ++rnd){
                int j = rnd*4096 + tid*16;
                int q = j ^ (((j>>7)&3)<<4);
                const char* src = wtb + (long)(kd*9 + (q>>12))*8192
                                      + (long)((q>>6)&63)*128 + khalf*64 + (q&63);
                gload16(src, sA + j);
            }
#pragma unroll
            for (int rnd=0; rnd<8; ++rnd){
                int j = rnd*4096 + tid*16;
                int q = j ^ (((j>>7)&3)<<4);
                const char* src = inb + (rowstart + (q>>6))*128 + khalf*64 + (q&63);
                gload16(src, sB + j);
            }
            if (tid < 32){
                int j = 32768 + tid*16;
                int q = j ^ (((j>>7)&3)<<4);
                const char* src = inb + (rowstart + (q>>6))*128 + khalf*64 + (q&63);
                gload16(src, sB + j);
            }
            __syncthreads();
#pragma unroll
            for (int kh=0; kh<3; ++kh){
                const int hh = my_h + kh - 1;
                if ((unsigned)hh >= 64u) continue;
                const int rr = (wave>>1) + kh;
#pragma unroll
                for (int kw=0; kw<3; ++kw){
                    const int tap_rel = kh*3 + kw;
                    bf16x8 Af[4], Bf[4];
#pragma unroll
                    for (int t=0;t<4;++t){
                        int qa = tap_rel*4096 + (t*16+ll)*64 + kg*16;
                        Af[t] = *(const bf16x8*)(sA + (qa ^ (((qa>>7)&3)<<4)));
                    }
#pragma unroll
                    for (int vt=0; vt<4; ++vt){
                        int vrel = rr*130 + my_w0 + vt*16 + ll + kw;
                        int qb = vrel*64 + kg*16;
                        Bf[vt] = *(const bf16x8*)(sB + (qb ^ (((qb>>7)&3)<<4)));
                    }
#pragma unroll
                    for (int vt=0; vt<4; ++vt)
#pragma unroll
                        for (int t=0; t<4; ++t)
                            acc[t][vt] = __builtin_amdgcn_mfma_f32_16x16x32_bf16(Af[t], Bf[vt], acc[t][vt], 0,0,0);
                }
            }
        }
    }

    if (AUX){
        bf16x8 Aa[2][4], Ba[2][4];
#pragma unroll
        for (int half=0; half<2; ++half){
            const int ko = half*32 + kg*8;
#pragma unroll
            for (int t=0;t<4;++t)
                Aa[half][t] = *(const bf16x8*)(auxw + (t*16+ll)*64 + ko);
#pragma unroll
            for (int vt=0; vt<4; ++vt)
                Ba[half][vt] = *(const bf16x8*)(aux + (pvb + vt*16 + ll)*64 + ko);
        }
#pragma unroll
        for (int half=0; half<2; ++half)
#pragma unroll
            for (int vt=0; vt<4; ++vt)
#pragma unroll
                for (int t=0;t<4;++t)
                    acc[t][vt] = __builtin_amdgcn_mfma_f32_16x16x32_bf16(Aa[half][t], Ba[half][vt], acc[t][vt], 0,0,0);
    }

#pragma unroll
    for (int vt=0; vt<4; ++vt){
        unsigned short* op = out + (pvb + vt*16 + ll)*64 + kg*4;
#pragma unroll
        for (int t=0;t<4;++t){
            float r0 = acc[t][vt][0], r1 = acc[t][vt][1], r2 = acc[t][vt][2], r3 = acc[t][vt][3];
            if (RELU){ r0=fmaxf(r0,0.f); r1=fmaxf(r1,0.f); r2=fmaxf(r2,0.f); r3=fmaxf(r3,0.f); }
            unsigned int lo = (unsigned)f2bf(r0) | ((unsigned)f2bf(r1)<<16);
            unsigned int hi = (unsigned)f2bf(r2) | ((unsigned)f2bf(r3)<<16);
            u32x2v q = {lo, hi};
            *(u32x2v*)(op + t*16) = q;
        }
    }
}

// ============ HEAD: conv3(x,wc1)+relu FUSED with tap-GEMM (R13 proven) ============
__global__ __launch_bounds__(256,2) void k_conv3h(
    const unsigned short* __restrict__ in, const unsigned short* __restrict__ wt,
    const unsigned short* __restrict__ wt2, unsigned short* __restrict__ t)
{
    __shared__ __align__(16) char sA[36864];
    __shared__ __align__(16) char sB[33280];

    const int tid  = threadIdx.x;
    const int lane = tid & 63;
    const int wave = tid >> 6;
    const int ll = lane & 15;
    const int kg = lane >> 4;
    const int bid = blockIdx.x;
    const int wid = ((bid & 7) * 192) + (bid >> 3);
    const int vbr = wid*256;
    const int d  = vbr >> 13;
    const int h0 = (vbr >> 7) & 63;
    const int my_h  = h0 + (wave >> 1);
    const int my_w0 = (wave & 1) * 64;
    const long pvb = (long)(d*64 + my_h)*PW + my_w0 + 1;

    const char* inb = (const char*)in;
    const char* wtb = (const char*)wt;

    f32x4 acc[4][4];
#pragma unroll
    for (int a=0;a<4;++a)
#pragma unroll
        for (int b=0;b<4;++b) acc[a][b] = (f32x4){0.f,0.f,0.f,0.f};

#pragma unroll
    for (int kd=0; kd<3; ++kd){
        const int dd = d + kd - 1;
        if ((unsigned)dd >= 48u) continue;
        const long rowstart = ((long)(dd*64 + h0 - 1)) * 130;
#pragma unroll
        for (int khalf=0; khalf<2; ++khalf){
            __syncthreads();
#pragma unroll
            for (int rnd=0; rnd<9; ++rnd){
                int j = rnd*4096 + tid*16;
                int q = j ^ (((j>>7)&3)<<4);
                const char* src = wtb + (long)(kd*9 + (q>>12))*8192
                                      + (long)((q>>6)&63)*128 + khalf*64 + (q&63);
                gload16(src, sA + j);
            }
#pragma unroll
            for (int rnd=0; rnd<8; ++rnd){
                int j = rnd*4096 + tid*16;
                int q = j ^ (((j>>7)&3)<<4);
                const char* src = inb + (rowstart + (q>>6))*128 + khalf*64 + (q&63);
                gload16(src, sB + j);
            }
            if (tid < 32){
                int j = 32768 + tid*16;
                int q = j ^ (((j>>7)&3)<<4);
                const char* src = inb + (rowstart + (q>>6))*128 + khalf*64 + (q&63);
                gload16(src, sB + j);
            }
            __syncthreads();
#pragma unroll
            for (int kh=0; kh<3; ++kh){
                const int hh = my_h + kh - 1;
                if ((unsigned)hh >= 64u) continue;
                const int rr = (wave>>1) + kh;
#pragma unroll
                for (int kw=0; kw<3; ++kw){
                    const int tap_rel = kh*3 + kw;
                    bf16x8 Af[4], Bf[4];
#pragma unroll
                    for (int tt=0;tt<4;++tt){
                        int qa = tap_rel*4096 + (tt*16+ll)*64 + kg*16;
                        Af[tt] = *(const bf16x8*)(sA + (qa ^ (((qa>>7)&3)<<4)));
                    }
#pragma unroll
                    for (int vt=0; vt<4; ++vt){
                        int vrel = rr*130 + my_w0 + vt*16 + ll + kw;
                        int qb = vrel*64 + kg*16;
                        Bf[vt] = *(const bf16x8*)(sB + (qb ^ (((qb>>7)&3)<<4)));
                    }
#pragma unroll
                    for (int vt=0; vt<4; ++vt)
#pragma unroll
                        for (int tt=0; tt<4; ++tt)
                            acc[tt][vt] = __builtin_amdgcn_mfma_f32_16x16x32_bf16(Af[tt], Bf[vt], acc[tt][vt], 0,0,0);
                }
            }
        }
    }

    // --- fused tap-GEMM epilogue ---
    __syncthreads();
    char* myL = sA + wave*8192;
#pragma unroll
    for (int vt=0; vt<4; ++vt){
        const int row = vt*16 + ll;
        const int sw = (row & 7) << 4;
#pragma unroll
        for (int tt=0;tt<4;++tt){
            float r0 = fmaxf(acc[tt][vt][0],0.f), r1 = fmaxf(acc[tt][vt][1],0.f);
            float r2 = fmaxf(acc[tt][vt][2],0.f), r3 = fmaxf(acc[tt][vt][3],0.f);
            unsigned int lo = (unsigned)f2bf(r0) | ((unsigned)f2bf(r1)<<16);
            unsigned int hi = (unsigned)f2bf(r2) | ((unsigned)f2bf(r3)<<16);
            u32x2v q = {lo, hi};
            int colb = kg*8 + tt*32;
            *(u32x2v*)(myL + row*128 + (colb ^ sw)) = q;
        }
    }
    f32x4 acc2[2][4];
#pragma unroll
    for (int a=0;a<2;++a)
#pragma unroll
        for (int b=0;b<4;++b) acc2[a][b] = (f32x4){0.f,0.f,0.f,0.f};
#pragma unroll
    for (int half=0; half<2; ++half){
        const int ko = half*32 + kg*8;
        bf16x8 afr[2];
#pragma unroll
        for (int tl=0;tl<2;++tl)
            afr[tl] = *(const bf16x8*)(wt2 + (tl*16+ll)*64 + ko);
#pragma unroll
        for (int vt=0; vt<4; ++vt){
            const int row = vt*16 + ll;
            const int sw = (row & 7) << 4;
            int colb = half*64 + kg*16;
            bf16x8 bfr = *(const bf16x8*)(myL + row*128 + (colb ^ sw));
#pragma unroll
            for (int tl=0;tl<2;++tl)
                acc2[tl][vt] = __builtin_amdgcn_mfma_f32_16x16x32_bf16(afr[tl], bfr, acc2[tl][vt], 0,0,0);
        }
    }
#pragma unroll
    for (int vt=0; vt<4; ++vt){
        long vx = pvb + vt*16 + ll;
#pragma unroll
        for (int tl=0;tl<2;++tl){
#pragma unroll
            for (int r=0;r<4;++r){
                int tap = tl*16 + kg*4 + r;
                if (tap < 27) t[(long)tap*PVOL + vx] = f2bf(acc2[tl][vt][r]);
            }
        }
    }
}

// ============ FUSED residual chain (R9, unchanged) ============
__global__ __launch_bounds__(256,3) void k_chain(const unsigned short* __restrict__ in,
        const unsigned short* __restrict__ Mt, unsigned short* __restrict__ out){
    __shared__ __align__(16) char sX[4][8192];
    const int lane = threadIdx.x & 63;
    const int wave = threadIdx.x >> 6;
    const int ll = lane & 15;
    const int kg = lane >> 4;
    const long vb = (long)blockIdx.x*256 + wave*64;
    char* myL = sX[wave];

    bf16x8 B[2][4];
#pragma unroll
    for (int half=0; half<2; ++half){
        const int ko = half*32 + kg*8;
#pragma unroll
        for (int vt=0; vt<4; ++vt)
            B[half][vt] = *(const bf16x8*)(in + (vb+vt*16+ll)*64 + ko);
    }

#pragma unroll
    for (int s=0; s<5; ++s){
        const unsigned short* wt = Mt + s*4096;
        bf16x8 A[2][4];
#pragma unroll
        for (int half=0; half<2; ++half){
            const int ko = half*32 + kg*8;
#pragma unroll
            for (int t=0;t<4;++t)
                A[half][t] = *(const bf16x8*)(wt + (t*16+ll)*64 + ko);
        }
        f32x4 acc[4][4];
#pragma unroll
        for (int a=0;a<4;++a)
#pragma unroll
            for (int b=0;b<4;++b) acc[a][b] = (f32x4){0.f,0.f,0.f,0.f};
#pragma unroll
        for (int half=0; half<2; ++half)
#pragma unroll
            for (int vt=0; vt<4; ++vt)
#pragma unroll
                for (int t=0;t<4;++t)
                    acc[t][vt] = __builtin_amdgcn_mfma_f32_16x16x32_bf16(A[half][t], B[half][vt], acc[t][vt], 0,0,0);

        if (s < 4){
#pragma unroll
            for (int vt=0; vt<4; ++vt){
                const int row = vt*16 + ll;
                const int sw = (row & 7) << 4;
#pragma unroll
                for (int t=0;t<4;++t){
                    float r0 = fmaxf(acc[t][vt][0],0.f), r1 = fmaxf(acc[t][vt][1],0.f);
                    float r2 = fmaxf(acc[t][vt][2],0.f), r3 = fmaxf(acc[t][vt][3],0.f);
                    unsigned int lo = (unsigned)f2bf(r0) | ((unsigned)f2bf(r1)<<16);
                    unsigned int hi = (unsigned)f2bf(r2) | ((unsigned)f2bf(r3)<<16);
                    u32x2v q = {lo, hi};
                    int colb = kg*8 + t*32;
                    *(u32x2v*)(myL + row*128 + (colb ^ sw)) = q;
                }
            }
#pragma unroll
            for (int half=0; half<2; ++half){
#pragma unroll
                for (int vt=0; vt<4; ++vt){
                    const int row = vt*16 + ll;
                    const int sw = (row & 7) << 4;
                    int colb = half*64 + kg*16;
                    B[half][vt] = *(const bf16x8*)(myL + row*128 + (colb ^ sw));
                }
            }
        } else {
#pragma unroll
            for (int vt=0; vt<4; ++vt){
                unsigned short* op = out + (vb+vt*16+ll)*64 + kg*4;
#pragma unroll
                for (int t=0;t<4;++t){
                    float r0 = fmaxf(acc[t][vt][0],0.f), r1 = fmaxf(acc[t][vt][1],0.f);
                    float r2 = fmaxf(acc[t][vt][2],0.f), r3 = fmaxf(acc[t][vt][3],0.f);
                    unsigned int lo = (unsigned)f2bf(r0) | ((unsigned)f2bf(r1)<<16);
                    unsigned int hi = (unsigned)f2bf(r2) | ((unsigned)f2bf(r3)<<16);
                    u32x2v q = {lo, hi};
                    *(u32x2v*)(op + t*16) = q;
                }
            }
        }
    }
}

// ============ head stage 2: 4 voxels/thread (R14 proven) ============
__global__ __launch_bounds__(256) void k_heads(const unsigned short* __restrict__ t,
        const float* __restrict__ bias, float* __restrict__ out){
    int g = blockIdx.x*256 + threadIdx.x;
    int v0 = g*4;
    int w0 = v0 & 127; int h = (v0>>7)&63; int d = v0>>13;
    long p0 = (long)(d*64+h)*PW + w0 + 1;
    float b0 = bias[0];
    float s0=b0, s1=b0, s2=b0, s3=b0;
#pragma unroll
    for (int kd=0;kd<3;++kd){
#pragma unroll
      for (int kh=0;kh<3;++kh){
#pragma unroll
        for (int kw=0;kw<3;++kw){
            const int tap = (kd*3+kh)*3+kw;
            const long dvp = (long)((kd-1)*64 + (kh-1))*PW + (kw-1);
            bool okdh = ((unsigned)(d+kd-1)<48u) && ((unsigned)(h+kh-1)<64u);
            const unsigned short* tp = t + (long)tap*PVOL;
            bool ok0 = okdh && ((unsigned)(w0+0+kw-1)<128u);
            bool ok1 = okdh && ((unsigned)(w0+1+kw-1)<128u);
            bool ok2 = okdh && ((unsigned)(w0+2+kw-1)<128u);
            bool ok3 = okdh && ((unsigned)(w0+3+kw-1)<128u);
            long a0 = ok0 ? (p0+0+dvp) : p0;
            long a1 = ok1 ? (p0+1+dvp) : p0;
            long a2 = ok2 ? (p0+2+dvp) : p0;
            long a3 = ok3 ? (p0+3+dvp) : p0;
            float x0 = bf2f(tp[a0]);
            float x1 = bf2f(tp[a1]);
            float x2 = bf2f(tp[a2]);
            float x3 = bf2f(tp[a3]);
            s0 += ok0 ? x0 : 0.f;
            s1 += ok1 ? x1 : 0.f;
            s2 += ok2 ? x2 : 0.f;
            s3 += ok3 ? x3 : 0.f;
        }
      }
    }
    f32x4 r = {s0,s1,s2,s3};
    *(f32x4*)(out + v0) = r;
}

// ============ pool stage 1: S3 cell sums (unchanged) ============
__global__ __launch_bounds__(256) void k_pool3(const unsigned short* __restrict__ in,
                                               float* __restrict__ S3){
    __shared__ float sm[32*68];
    int tid = threadIdx.x;
    int cg = tid & 7, part = tid >> 3;
    int cell = blockIdx.x;
    int Z = cell >> 8, Y = (cell >> 4) & 15, X = cell & 15;
    float a[8];
#pragma unroll
    for (int j=0;j<8;++j) a[j]=0.f;
#pragma unroll
    for (int j=0;j<3;++j){
        int i = part*3 + j;
        int di = i >> 5, rem = i & 31, hi = rem >> 3, wi = rem & 7;
        long p = ((long)((3*Z+di)*64 + 4*Y+hi))*PW + 8*X+wi + 1;
        u32x4v q = *(const u32x4v*)(in + p*64 + cg*8);
#pragma unroll
        for (int e=0;e<4;++e){ a[e*2] += bflo(q[e]); a[e*2+1] += bfhi(q[e]); }
    }
#pragma unroll
    for (int j=0;j<8;++j) sm[part*68 + cg*8 + j] = a[j];
    __syncthreads();
    if (tid < 64){
        float s=0.f;
        for (int r=0;r<32;++r) s += sm[r*68 + tid];
        S3[tid*4096 + cell] = s;
    }
}

// ============ p2 sums from S3 (unchanged) ============
__global__ __launch_bounds__(256) void k_pool2(const float* __restrict__ S3,
                                               float* __restrict__ P2){
    int idx = blockIdx.x*256 + threadIdx.x;
    int cell = idx & 511; int c = idx >> 9;
    int z = cell >> 6, y = (cell >> 3) & 7, x = cell & 7;
    const float* b = S3 + c*4096;
    float s = 0.f;
#pragma unroll
    for (int a2=0;a2<2;++a2)
#pragma unroll
        for (int b2=0;b2<2;++b2)
#pragma unroll
            for (int e=0;e<2;++e)
                s += b[((2*z+a2)<<8) + ((2*y+b2)<<4) + (2*x+e)];
    P2[c*512 + cell] = s;
}

// ============ g + gc from S3 (unchanged) ============
__global__ void k_gcm(const float* __restrict__ S3, const float* __restrict__ wp0,
                      float* __restrict__ gc){
    __shared__ float sm[4][64];
    __shared__ float sg[64];
    int tid = threadIdx.x;
    int c = tid & 63, part = tid >> 6;
    float s = 0.f;
    const float* row = S3 + c*4096 + part*1024;
    for (int i=0;i<1024;i+=4){
        f32x4 q = *(const f32x4*)(row + i);
        s += q[0]+q[1]+q[2]+q[3];
    }
    sm[part][c] = s;
    __syncthreads();
    if (tid < 64){
        sg[tid] = (sm[0][tid]+sm[1][tid]+sm[2][tid]+sm[3][tid]) * (1.0f/(float)VOL);
    }
    __syncthreads();
    if (tid < 64){
        float g=0.f;
        for (int ci=0;ci<64;++ci) g += wp0[tid*64+ci]*sg[ci];
        gc[tid] = g;
    }
}

// ============ p4 sums (unchanged) ============
__global__ __launch_bounds__(256) void k_pool4(const unsigned short* __restrict__ in,
                                               float* __restrict__ P4){
    __shared__ float sm[32*68];
    int tid = threadIdx.x;
    int cg = tid & 7, part = (tid >> 3) & 3, slot = tid >> 5;
    int cell = blockIdx.x*8 + slot;
    int z = cell / 800; int rem = cell - z*800; int y = rem / 25; int x = rem - y*25;
    int a2 = part >> 1, b2 = part & 1;
    float a[8];
#pragma unroll
    for (int j=0;j<8;++j) a[j]=0.f;
#pragma unroll
    for (int e=0;e<5;++e){
        long p = ((long)((2*z+a2)*64 + 2*y+b2))*PW + 5*x+e + 1;
        u32x4v q = *(const u32x4v*)(in + p*64 + cg*8);
#pragma unroll
        for (int k=0;k<4;++k){ a[k*2] += bflo(q[k]); a[k*2+1] += bfhi(q[k]); }
    }
#pragma unroll
    for (int j=0;j<8;++j) sm[(slot*4+part)*68 + cg*8 + j] = a[j];
    __syncthreads();
#pragma unroll
    for (int r=0;r<2;++r){
        int o = r*256 + tid;
        int c = o >> 3, s = o & 7;
        float v = sm[(s*4+0)*68 + c] + sm[(s*4+1)*68 + c]
                + sm[(s*4+2)*68 + c] + sm[(s*4+3)*68 + c];
        P4[(long)c*19200 + blockIdx.x*8 + s] = v;
    }
}

// ============ 1x1 conv fp32 on pooled SUMS (unchanged) ============
__global__ void k_conv1(const float* __restrict__ in, const float* __restrict__ wt,
                        float* __restrict__ out, int vol, float scale){
    int v = blockIdx.x*256 + threadIdx.x;
    if (v >= vol) return;
    float acc[64];
#pragma unroll
    for (int i=0;i<64;++i) acc[i]=0.f;
    for (int ci=0; ci<64; ++ci){
        float xv = in[ci*vol + v];
        const float* wr = wt + ci*64;
#pragma unroll
        for (int co=0; co<64; ++co) acc[co] = fmaf(wr[co], xv, acc[co]);
    }
    float* op = out + (long)v*64;
#pragma unroll
    for (int q=0;q<16;++q){
        f32x4 t = {acc[q*4]*scale, acc[q*4+1]*scale, acc[q*4+2]*scale, acc[q*4+3]*scale};
        *(f32x4*)(op + q*4) = t;
    }
}

// ============ trilinear gather ============
__device__ __forceinline__ void tri_setup(int d,int h,int w,int gd,int gh,int gw,
                                          int* o, float* wt){
    float fz = (d+0.5f)*((float)gd/(float)DD) - 0.5f;
    float fy = (h+0.5f)*((float)gh/(float)HH) - 0.5f;
    float fx = (w+0.5f)*((float)gw/(float)WW) - 0.5f;
    float z0f = floorf(fz), y0f = floorf(fy), x0f = floorf(fx);
    float tz = fz - z0f, ty = fy - y0f, tx = fx - x0f;
    int z0 = (int)z0f, y0 = (int)y0f, x0 = (int)x0f;
    int z1 = z0+1, y1 = y0+1, x1 = x0+1;
    z0 = min(max(z0,0),gd-1); z1 = min(max(z1,0),gd-1);
    y0 = min(max(y0,0),gh-1); y1 = min(max(y1,0),gh-1);
    x0 = min(max(x0,0),gw-1); x1 = min(max(x1,0),gw-1);
    o[0] = (z0*gh+y0)*gw+x0; wt[0] = (1-tz)*(1-ty)*(1-tx);
    o[1] = (z0*gh+y0)*gw+x1; wt[1] = (1-tz)*(1-ty)*tx;
    o[2] = (z0*gh+y1)*gw+x0; wt[2] = (1-tz)*ty*(1-tx);
    o[3] = (z0*gh+y1)*gw+x1; wt[3] = (1-tz)*ty*tx;
    o[4] = (z1*gh+y0)*gw+x0; wt[4] = tz*(1-ty)*(1-tx);
    o[5] = (z1*gh+y0)*gw+x1; wt[5] = tz*(1-ty)*tx;
    o[6] = (z1*gh+y1)*gw+x0; wt[6] = tz*ty*(1-tx);
    o[7] = (z1*gh+y1)*gw+x1; wt[7] = tz*ty*tx;
}

// out = relu((xc + 0.25*(gc + up(p2)+up(p3)+up(p4)))/2)
// R13 proven form: 256-thread full-voxel blocks, XCD swizzle, nt fp32 stores
__global__ __launch_bounds__(256) void k_combine(
        const unsigned short* __restrict__ xc, const float* __restrict__ gc,
        const float* __restrict__ p2, const float* __restrict__ p3,
        const float* __restrict__ p4, float* __restrict__ xout,
        unsigned short* __restrict__ xv){
    int tid = threadIdx.x;
    const int bid = blockIdx.x;
    const int wid = ((bid & 7) * 192) + (bid >> 3);   // 1536 blocks, bijective
    long v = (long)wid*256 + tid;
    int w = v & 127; int h = (v>>7)&63; int d = v>>13;
    long p = (long)(d*64+h)*PW + w + 1;
    int o2[8], o3[8], o4[8];
    float w2_[8], w3_[8], w4_[8];
    tri_setup(d,h,w, 8,8,8,    o2, w2_);
    tri_setup(d,h,w, 16,16,16, o3, w3_);
    tri_setup(d,h,w, 24,32,25, o4, w4_);
#pragma unroll
    for (int half=0; half<2; ++half){
        float res[32];
#pragma unroll
        for (int j=0;j<32;++j) res[j] = gc[half*32+j];
#pragma unroll
        for (int t=0;t<8;++t){
            const float* b2 = p2 + (long)o2[t]*64 + half*32;
#pragma unroll
            for (int q=0;q<8;++q){
                f32x4 x4 = *(const f32x4*)(b2 + q*4);
                res[q*4+0] = fmaf(w2_[t], x4[0], res[q*4+0]);
                res[q*4+1] = fmaf(w2_[t], x4[1], res[q*4+1]);
                res[q*4+2] = fmaf(w2_[t], x4[2], res[q*4+2]);
                res[q*4+3] = fmaf(w2_[t], x4[3], res[q*4+3]);
            }
        }
#pragma unroll
        for (int t=0;t<8;++t){
            const float* b3 = p3 + (long)o3[t]*64 + half*32;
#pragma unroll
            for (int q=0;q<8;++q){
                f32x4 x4 = *(const f32x4*)(b3 + q*4);
                res[q*4+0] = fmaf(w3_[t], x4[0], res[q*4+0]);
                res[q*4+1] = fmaf(w3_[t], x4[1], res[q*4+1]);
                res[q*4+2] = fmaf(w3_[t], x4[2], res[q*4+2]);
                res[q*4+3] = fmaf(w3_[t], x4[3], res[q*4+3]);
            }
        }
#pragma unroll
        for (int t=0;t<8;++t){
            const float* b4 = p4 + (long)o4[t]*64 + half*32;
#pragma unroll
            for (int q=0;q<8;++q){
                f32x4 x4 = *(const f32x4*)(b4 + q*4);
                res[q*4+0] = fmaf(w4_[t], x4[0], res[q*4+0]);
                res[q*4+1] = fmaf(w4_[t], x4[1], res[q*4+1]);
                res[q*4+2] = fmaf(w4_[t], x4[2], res[q*4+2]);
                res[q*4+3] = fmaf(w4_[t], x4[3], res[q*4+3]);
            }
        }
        const u32x4v* xq = (const u32x4v*)(xc + p*64 + half*32);
#pragma unroll
        for (int q=0;q<4;++q){
            u32x4v qv = xq[q];
            unsigned int pk[4];
#pragma unroll
            for (int e=0;e<4;++e){
                int j = q*8 + e*2;
                float r0 = fmaxf((bflo(qv[e]) + 0.25f*res[j])*0.5f, 0.f);
                float r1 = fmaxf((bfhi(qv[e]) + 0.25f*res[j+1])*0.5f, 0.f);
                __builtin_nontemporal_store(r0, &xout[(long)(half*32+j)*VOL + v]);
                __builtin_nontemporal_store(r1, &xout[(long)(half*32+j+1)*VOL + v]);
                pk[e] = (unsigned)f2bf(r0) | ((unsigned)f2bf(r1)<<16);
            }
            u32x4v pq = {pk[0],pk[1],pk[2],pk[3]};
            *(u32x4v*)(xv + p*64 + half*32 + q*8) = pq;
        }
    }
}

// ================= workspace layout (bytes) =================
constexpr long RPV = GUARD + PVBYTES + GUARD;
constexpr long OFF_PV0R = 0;
constexpr long OFF_PV1R = RPV;
constexpr long OFF_WA1 = 2*RPV;
constexpr long OFF_WA2 = OFF_WA1 + 221184;
constexpr long OFF_WC1 = OFF_WA2 + 221184;
constexpr long OFF_NIN = OFF_WC1 + 221184;
constexpr long OFF_MT  = OFF_NIN + 8192;
constexpr long OFF_WT2 = OFF_MT + 40960;
constexpr long OFF_WPT = OFF_WT2 + 4096;
constexpr long OFF_GC  = OFF_WPT + 49152;
constexpr long OFF_P2  = OFF_GC + 256;
constexpr long OFF_P2C = OFF_P2 + 131072;
constexpr long OFF_S3  = OFF_P2C + 131072;
constexpr long OFF_P3C = OFF_S3 + 1048576;
constexpr long OFF_P4  = OFF_P3C + 1048576;
constexpr long OFF_P4C = OFF_P4 + 4915200;
// end ~= 115.4 MB

extern "C" void kernel_launch(void* const* d_in, const int* in_sizes, int n_in,
                              void* d_out, int out_size, void* d_ws, size_t ws_size,
                              hipStream_t stream) {
    const float* fvl  = (const float*)d_in[0];
    const float* w_a1 = (const float*)d_in[1];
    const float* w_a2 = (const float*)d_in[2];
    const float* wnin = (const float*)d_in[3];
    const float* w1s  = (const float*)d_in[4];
    const float* w2s  = (const float*)d_in[5];
    const float* wp0  = (const float*)d_in[6];
    const float* wp1  = (const float*)d_in[7];
    const float* wp2  = (const float*)d_in[8];
    const float* wp3  = (const float*)d_in[9];
    const float* wc1  = (const float*)d_in[10];
    const float* wc2  = (const float*)d_in[11];
    const float* bc   = (const float*)d_in[12];

    char* ws = (char*)d_ws;
    unsigned short* PV0  = (unsigned short*)(ws + OFF_PV0R + GUARD);
    unsigned short* PV1  = (unsigned short*)(ws + OFF_PV1R + GUARD);
    unsigned short* wa1t = (unsigned short*)(ws + OFF_WA1);
    unsigned short* wa2t = (unsigned short*)(ws + OFF_WA2);
    unsigned short* wc1t = (unsigned short*)(ws + OFF_WC1);
    unsigned short* nint = (unsigned short*)(ws + OFF_NIN);
    unsigned short* Mt   = (unsigned short*)(ws + OFF_MT);
    unsigned short* wt2  = (unsigned short*)(ws + OFF_WT2);
    float* wpt  = (float*)(ws + OFF_WPT);
    float* gc   = (float*)(ws + OFF_GC);
    float* p2   = (float*)(ws + OFF_P2);
    float* p2c  = (float*)(ws + OFF_P2C);
    float* S3   = (float*)(ws + OFF_S3);
    float* p3c  = (float*)(ws + OFF_P3C);
    float* p4   = (float*)(ws + OFF_P4);
    float* p4c  = (float*)(ws + OFF_P4C);

    float* Xout = (float*)d_out;
    float* Cout = Xout + (long)NC*VOL;
    unsigned short* Tbuf = PV1;     // head t bf16 [27][PVOL], reuses PV1 (free after combine)

    const int GBR = VOL/256;     // 1536
    const int GBP = PVOL/256;    // 1560

    // zero only the pad columns (1.5MB instead of 102MB of memset)
    k_zeropad<<<384,256,0,stream>>>(PV0, PV1);

    // all weight prep in ONE launch
    k_prep_all<<<1448,256,0,stream>>>(w_a1, w_a2, wc1, wnin, wc2, w1s, w2s,
                                      wp1, wp2, wp3,
                                      wa1t, wa2t, wc1t, nint, wt2, Mt, wpt);
    k_tobf16v<<<VOL/64,256,0,stream>>>(fvl, PV0);

    // stage A/B: conv3 chain
    k_conv3m<false,false><<<GBR,256,0,stream>>>(PV0, wa1t, nullptr, nullptr, PV1);
    k_conv3m<true,false><<<GBR,256,0,stream>>>(PV1, wa2t, PV0, nint, PV0);

    // stage C: fused 5-stage residual chain PV0 -> PV1 (one kernel)
    k_chain<<<GBP,256,0,stream>>>(PV0, Mt, PV1);

    // stage D: pool pyramid
    k_pool3<<<4096,256,0,stream>>>(PV1, S3);
    k_gcm<<<1,256,0,stream>>>(S3, wp0, gc);
    k_pool2<<<128,256,0,stream>>>(S3, p2);
    k_pool4<<<2400,256,0,stream>>>(PV1, p4);
    k_conv1<<<2,256,0,stream>>>(p2, wpt + 0*4096, p2c, 512,   1.0f/768.0f);
    k_conv1<<<16,256,0,stream>>>(S3, wpt + 1*4096, p3c, 4096, 1.0f/96.0f);
    k_conv1<<<75,256,0,stream>>>(p4, wpt + 2*4096, p4c, 19200, 1.0f/20.0f);

    // combine (fused, proven): Xout fp32 + padded bf16 x into PV0
    k_combine<<<GBR,256,0,stream>>>(PV1, gc, p2c, p3c, p4c, Xout, PV0);

    // head: conv3(x,wc1)+relu fused with tap-GEMM -> Tbuf (PV1); then gather-sum
    k_conv3h<<<GBR,256,0,stream>>>(PV0, wc1t, wt2, Tbuf);
    k_heads<<<384,256,0,stream>>>(Tbuf, bc, Cout);
}